// Round 9
// baseline (138.807 us; speedup 1.0000x reference)
//
#include <hip/hip_runtime.h>
#include <hip/hip_bf16.h>

typedef __attribute__((ext_vector_type(8))) short short8;
typedef __attribute__((ext_vector_type(4))) float f32x4;

__device__ inline short f2bf(float x) {
    union { __hip_bfloat16 b; short s; } u;
    u.b = __float2bfloat16(x);
    return u.s;
}
__device__ inline float bf2f(short s) {
    union { __hip_bfloat16 b; short s; } u;
    u.s = s;
    return __bfloat162float(u.b);
}

#define GLDS16(g, l) __builtin_amdgcn_global_load_lds( \
    (const __attribute__((address_space(1))) void*)(g), \
    (__attribute__((address_space(3))) void*)(l), 16, 0, 0)

// ---------------- merged transpose + f32->bf16 convert (all weights + features) ----
__global__ void transpose_all(const float* __restrict__ W1, const float* __restrict__ features,
                              const float* __restrict__ W2, const float* __restrict__ Wc,
                              const float* __restrict__ Wb,
                              short* __restrict__ W1t, short* __restrict__ featT,
                              short* __restrict__ W2t, short* __restrict__ Wht) {
    int id = blockIdx.x;
    const float* in;
    short* out;
    int R, C, r0, c0;
    if (id < 12544) {
        in = W1; out = W1t; R = 12544; C = 1024;
        r0 = (id % 392) * 32; c0 = (id / 392) * 32;
    } else if (id < 13808) {
        int f = id - 12544;
        int img = f / 632, g = f % 632;
        in = features + (long)img * 640000;
        out = featT + (long)img * 640000;
        R = 256; C = 2500;
        r0 = (g % 8) * 32; c0 = (g / 8) * 32;
    } else if (id < 14832) {
        int g = id - 13808;
        in = W2; out = W2t; R = 1024; C = 1024;
        r0 = (g % 32) * 32; c0 = (g / 32) * 32;
    } else if (id < 14928) {
        int g = id - 14832;
        in = Wc; out = Wht; R = 1024; C = 81;
        r0 = (g % 32) * 32; c0 = (g / 32) * 32;
    } else {
        int g = id - 14928;
        in = Wb; out = Wht + 81 * 1024; R = 1024; C = 324;
        r0 = (g % 32) * 32; c0 = (g / 32) * 32;
    }
    __shared__ float tile[32][33];
    int tr = threadIdx.x >> 5;
    int tc = threadIdx.x & 31;
    #pragma unroll
    for (int i = 0; i < 4; ++i) {
        int r = r0 + tr + i * 8;
        int c = c0 + tc;
        float v = 0.f;
        if (c < C) v = in[(long)r * C + c];
        tile[tr + i * 8][tc] = v;
    }
    __syncthreads();
    #pragma unroll
    for (int i = 0; i < 4; ++i) {
        int n = c0 + tr + i * 8;
        int k = r0 + tc;
        if (n < C) out[(long)n * R + k] = f2bf(tile[tc][tr + i * 8]);
    }
}

// ---------------- ROI-align v3: 16B vector loads, wave-half corner split ----------
__global__ __launch_bounds__(256) void roi_align_v3(const short* __restrict__ featT,
                                                    const float* __restrict__ props,
                                                    short* __restrict__ Xb) {
    int roi = blockIdx.x;
    int img = roi >> 9;
    __shared__ unsigned int soffB[784];
    __shared__ float swB[784];
    __shared__ float pbox[4];
    __shared__ short outb[49 * 264];
    int tid = threadIdx.x;
    if (tid < 4) pbox[tid] = props[roi * 4 + tid];
    __syncthreads();
    if (tid < 196) {
        float x1 = pbox[0] * 0.0625f, y1 = pbox[1] * 0.0625f;
        float x2 = pbox[2] * 0.0625f, y2 = pbox[3] * 0.0625f;
        float rw = fmaxf(x2 - x1, 1.0f), rh = fmaxf(y2 - y1, 1.0f);
        int p = tid >> 2, q = tid & 3;
        int py = p / 7, px = p % 7;
        int sy = q >> 1, sx = q & 1;
        int gy = py * 2 + sy, gx = px * 2 + sx;
        float gyv = ((float)gy + 0.5f) * 0.5f;
        float gxv = ((float)gx + 0.5f) * 0.5f;
        float ys = y1 + gyv * (rh * (1.0f / 7.0f));
        float xs = x1 + gxv * (rw * (1.0f / 7.0f));
        ys = fminf(fmaxf(ys, 0.0f), 49.0f);
        xs = fminf(fmaxf(xs, 0.0f), 49.0f);
        float y0f = floorf(ys), x0f = floorf(xs);
        int y0 = (int)y0f, x0 = (int)x0f;
        int y1i = min(y0 + 1, 49), x1i = min(x0 + 1, 49);
        float ly = ys - y0f, lx = xs - x0f;
        float hy = 1.f - ly, hx = 1.f - lx;
        int b00 = (y0 * 50 + x0) << 9;
        int ddx = (x1i - x0) << 9;
        int ddy = (y1i - y0) * 25600;
        int t4 = tid << 2;
        soffB[t4 + 0] = b00;             swB[t4 + 0] = hy * hx * 0.25f;
        soffB[t4 + 1] = b00 + ddx;       swB[t4 + 1] = hy * lx * 0.25f;
        soffB[t4 + 2] = b00 + ddy;       swB[t4 + 2] = ly * hx * 0.25f;
        soffB[t4 + 3] = b00 + ddy + ddx; swB[t4 + 3] = ly * lx * 0.25f;
    }
    __syncthreads();
    int w = tid >> 6, l = tid & 63;
    int half = l >> 5, ch16 = l & 31;
    const char* fbase = (const char*)featT + (long)img * 1280000 + (ch16 << 4);
    for (int p = w; p < 49; p += 4) {
        float acc[8] = {};
        #pragma unroll
        for (int ld = 0; ld < 8; ++ld) {
            int idx = (p << 4) + (ld << 1) + half;
            unsigned int off = soffB[idx];
            float wgt = swB[idx];
            short8 v = *(const short8*)(fbase + off);
            union { short8 s; unsigned int u[4]; } uv;
            uv.s = v;
            #pragma unroll
            for (int k2 = 0; k2 < 4; ++k2) {
                unsigned int u = uv.u[k2];
                float flo = __uint_as_float(u << 16);
                float fhi = __uint_as_float(u & 0xffff0000u);
                acc[k2 * 2]     += wgt * flo;
                acc[k2 * 2 + 1] += wgt * fhi;
            }
        }
        short8 o;
        #pragma unroll
        for (int j = 0; j < 8; ++j) {
            float t = acc[j] + __shfl_xor(acc[j], 32);
            o[j] = f2bf(t);
        }
        if (half == 0) *(short8*)&outb[p * 264 + (ch16 << 3)] = o;
    }
    __syncthreads();
    int c = tid / 49, r = tid % 49;
    short* xrow = Xb + (long)roi * 12544;
    #pragma unroll 1
    for (int i = 0; i < 49; ++i) {
        xrow[tid + i * 256] = outb[r * 264 + c];
        c += 5; r += 11;
        if (r >= 49) { r -= 49; c += 1; }
    }
}

// ----- 128x64 MFMA GEMM: glds staging + XOR swizzle + dbuf 2-phase, 48KB LDS -----
// C = A[M,K] @ Bt[N,K]^T; 3 blocks/CU resident.
// MODE 0: partial -> bf16 at Cout + z*M*N (no bias)
// MODE 1: bias+relu -> bf16
// MODE 2: (bc|bb|0) bias -> f32
template <int MODE>
__global__ __launch_bounds__(256) void gemm64(const short* __restrict__ A,
                                              const short* __restrict__ Bt,
                                              const float* __restrict__ bias,
                                              const float* __restrict__ bias2,
                                              void* __restrict__ Cout,
                                              int M, int N, int K, int kbase, int krem) {
    __shared__ short As[2][128 * 64];   // 2 x 16KB
    __shared__ short Bs[2][64 * 64];    // 2 x 8KB  -> 48KB total
    // bijective XCD-chunked remap (m204)
    int gx = gridDim.x, gy = gridDim.y;
    int nwg = gx * gy * gridDim.z;
    int orig = blockIdx.x + gx * (blockIdx.y + gy * blockIdx.z);
    int wg = orig;
    if ((nwg & 7) == 0 && nwg >= 64) {
        int q = nwg >> 3;
        wg = (orig & 7) * q + (orig >> 3);
    }
    int bx_ = wg % gx;
    int tmp = wg / gx;
    int by_ = tmp % gy;
    int bz_ = tmp / gy;
    int ksteps = kbase + (bz_ < krem ? 1 : 0);
    long kbeg = ((long)bz_ * kbase + (bz_ < krem ? bz_ : krem)) * 64;
    int m0 = by_ * 128, n0 = bx_ * 64;
    int tid = threadIdx.x;
    int w = tid >> 6, lane = tid & 63;
    int wr = w >> 1, wc = w & 1;          // 2x2 waves over (128m, 64n)
    int lr = lane & 15, lk = lane >> 4;
    int srow = tid >> 3;                  // 0..31
    int sbx = ((tid & 7) ^ (srow & 7)) << 4;
    const char* Ag = (const char*)A + ((long)(m0 + srow) * K + kbeg) * 2 + sbx;
    const char* Bg = (const char*)Bt + ((long)(n0 + srow) * K + kbeg) * 2 + sbx;
    const long rstep = (long)K * 64;      // 32 rows * K * 2B
    char* As0 = (char*)&As[0][0];
    char* Bs0 = (char*)&Bs[0][0];
    int wofs = w << 10;
    int sw = (lr & 7) << 4;
    f32x4 acc[4][2] = {};

    // stage tile t into buffer b: A = 4 passes (128 rows), B = 2 passes (64 rows)
    #define STAGE(t, b) do { \
        const char* _a = Ag + (long)(t) * 128; \
        const char* _b = Bg + (long)(t) * 128; \
        char* _ad = As0 + ((b) << 14) + wofs; \
        char* _bd = Bs0 + ((b) << 13) + wofs; \
        GLDS16(_a + 0 * rstep, _ad + 0 * 4096); \
        GLDS16(_a + 1 * rstep, _ad + 1 * 4096); \
        GLDS16(_a + 2 * rstep, _ad + 2 * 4096); \
        GLDS16(_a + 3 * rstep, _ad + 3 * 4096); \
        GLDS16(_b + 0 * rstep, _bd + 0 * 4096); \
        GLDS16(_b + 1 * rstep, _bd + 1 * 4096); \
    } while (0)

    STAGE(0, 0);
    __syncthreads();
    int cur = 0;
    for (int t = 0; t < ksteps; ++t) {
        if (t + 1 < ksteps) {   // issue next-tile stage BEFORE compute
            STAGE(t + 1, cur ^ 1);
        }
        const char* as = As0 + (cur << 14);
        const char* bs = Bs0 + (cur << 13);
        #pragma unroll
        for (int kk = 0; kk < 2; ++kk) {
            short8 av[4], bv[2];
            #pragma unroll
            for (int f = 0; f < 4; ++f)
                av[f] = *(const short8*)(as + (wr * 64 + f * 16 + lr) * 128 + ((kk * 64 + lk * 16) ^ sw));
            #pragma unroll
            for (int f = 0; f < 2; ++f)
                bv[f] = *(const short8*)(bs + (wc * 32 + f * 16 + lr) * 128 + ((kk * 64 + lk * 16) ^ sw));
            #pragma unroll
            for (int fm = 0; fm < 4; ++fm)
                #pragma unroll
                for (int fn = 0; fn < 2; ++fn)
                    acc[fm][fn] = __builtin_amdgcn_mfma_f32_16x16x32_bf16(av[fm], bv[fn], acc[fm][fn], 0, 0, 0);
        }
        __syncthreads();
        cur ^= 1;
    }
    #undef STAGE

    #pragma unroll
    for (int fm = 0; fm < 4; ++fm) {
        #pragma unroll
        for (int fn = 0; fn < 2; ++fn) {
            int col = n0 + wc * 32 + fn * 16 + lr;
            float bv = 0.f;
            if (MODE == 1) bv = bias[col];
            if (MODE == 2) bv = (col < 81) ? bias[col] : (col < 405 ? bias2[col - 81] : 0.f);
            #pragma unroll
            for (int j = 0; j < 4; ++j) {
                int row = m0 + wr * 64 + fm * 16 + lk * 4 + j;
                float v = acc[fm][fn][j];
                if (MODE == 0) {
                    ((short*)Cout)[(long)bz_ * M * N + (long)row * N + col] = f2bf(v);
                } else if (MODE == 1) {
                    ((short*)Cout)[(long)row * N + col] = f2bf(fmaxf(v + bv, 0.f));
                } else {
                    ((float*)Cout)[(long)row * N + col] = v + bv;
                }
            }
        }
    }
}

// ---------------- split-K reduce: H1 = relu(sum_s P[s] + b1) -> bf16 ----------------
__global__ void reduceN_relu(const short* __restrict__ P, const float* __restrict__ bias,
                             short* __restrict__ Hout, int nsl) {
    long i0 = ((long)blockIdx.x * 256 + threadIdx.x) * 8;
    int col = (int)(i0 & 1023);
    float v[8];
    #pragma unroll
    for (int j = 0; j < 8; ++j) v[j] = bias[col + j];
    for (int s = 0; s < nsl; ++s) {
        short8 p = *(const short8*)(P + (long)s * 1048576 + i0);
        #pragma unroll
        for (int j = 0; j < 8; ++j) v[j] += bf2f(p[j]);
    }
    short8 o;
    #pragma unroll
    for (int j = 0; j < 8; ++j) o[j] = f2bf(fmaxf(v[j], 0.f));
    *(short8*)(Hout + i0) = o;
}

// ---------------- softmax + decode + valid ----------------
__global__ void head_epilogue(const float* __restrict__ O,      // [1024][448]
                              const float* __restrict__ props,
                              float* __restrict__ Boxes,
                              float* __restrict__ Scores,
                              unsigned char* __restrict__ Valid) {
    int roi = blockIdx.x;
    int lane = threadIdx.x;  // 64
    const float* o = O + (long)roi * 448;
    float m = -1e30f;
    for (int i = lane; i < 81; i += 64) m = fmaxf(m, o[i]);
    for (int off = 32; off > 0; off >>= 1) m = fmaxf(m, __shfl_xor(m, off));
    float ssum = 0.f;
    for (int i = lane; i < 81; i += 64) ssum += expf(o[i] - m);
    for (int off = 32; off > 0; off >>= 1) ssum += __shfl_xor(ssum, off);
    float inv = 1.0f / ssum;
    int img = roi >> 9, rb = roi & 511;
    float px1 = props[roi * 4 + 0], py1 = props[roi * 4 + 1];
    float px2 = props[roi * 4 + 2], py2 = props[roi * 4 + 3];
    float w = px2 - px1, h = py2 - py1;
    float cx = px1 + 0.5f * w, cy = py1 + 0.5f * h;
    long obase = (long)img * 40960 + (long)rb * 80;
    const float DW = 4.135166556742356f;
    for (int t = lane; t < 80; t += 64) {
        int cls = t + 1;
        float score = expf(o[cls] - m) * inv;
        const float* d = o + 81 + cls * 4;
        float dx = d[0] * 0.1f, dy = d[1] * 0.1f;
        float dw = fminf(d[2] * 0.2f, DW);
        float dh = fminf(d[3] * 0.2f, DW);
        float pcx = dx * w + cx, pcy = dy * h + cy;
        float pw = expf(dw) * w, ph = expf(dh) * h;
        float x1 = pcx - 0.5f * pw, y1 = pcy - 0.5f * ph;
        float x2 = pcx + 0.5f * pw, y2 = pcy + 0.5f * ph;
        x1 = fminf(fmaxf(x1, 0.f), 800.f); y1 = fminf(fmaxf(y1, 0.f), 800.f);
        x2 = fminf(fmaxf(x2, 0.f), 800.f); y2 = fminf(fmaxf(y2, 0.f), 800.f);
        float wv = x2 - x1, hv = y2 - y1;
        long oi = obase + t;
        Boxes[oi * 4 + 0] = x1; Boxes[oi * 4 + 1] = y1;
        Boxes[oi * 4 + 2] = x2; Boxes[oi * 4 + 3] = y2;
        Scores[oi] = score;
        Valid[oi] = (score >= 0.05f && wv >= 1.0f && hv >= 1.0f) ? 1 : 0;
    }
}

// ---------------- fused compaction + greedy NMS (one block per image) ----------------
__global__ void nms_fused(const float* __restrict__ Boxes, const float* __restrict__ Scores,
                          const unsigned char* __restrict__ Valid,
                          float* __restrict__ CB, int* __restrict__ CL,
                          float* __restrict__ CSw, float* __restrict__ out) {
    int img = blockIdx.x;
    int tid = threadIdx.x;  // 256
    const int SEG = 160;
    const unsigned char* V = Valid + (long)img * 40960;
    int j0 = tid * SEG;
    const unsigned int* V4 = (const unsigned int*)(V + j0);
    int c = 0;
    #pragma unroll
    for (int k = 0; k < 40; ++k) {
        unsigned int u = V4[k];
        c += (int)((u * 0x01010101u) >> 24);
    }
    __shared__ int cnt[256];
    cnt[tid] = c;
    __syncthreads();
    for (int d = 1; d < 256; d <<= 1) {
        int v = (tid >= d) ? cnt[tid - d] : 0;
        __syncthreads();
        cnt[tid] += v;
        __syncthreads();
    }
    int pos = cnt[tid] - c;
    const float* B = Boxes + (long)img * 40960 * 4;
    const float* S = Scores + (long)img * 40960;
    float* cb = CB + (long)img * 40960 * 4;
    float* sc = CSw + (long)img * 40960;
    int* cl = CL + (long)img * 40960;
    if (c > 0) {
        for (int k = 0; k < SEG; ++k) {
            int j = j0 + k;
            if (V[j]) {
                sc[pos] = S[j];
                cb[pos * 4 + 0] = B[j * 4 + 0]; cb[pos * 4 + 1] = B[j * 4 + 1];
                cb[pos * 4 + 2] = B[j * 4 + 2]; cb[pos * 4 + 3] = B[j * 4 + 3];
                cl[pos] = (j % 80) + 1;
                ++pos;
            }
        }
    }
    int Vn = cnt[255];
    for (int i = tid; i < 400; i += 256) out[img * 400 + i] = 0.f;
    if (tid < 100) {
        out[800 + img * 100 + tid] = 0.f;
        out[1000 + img * 100 + tid] = 0.f;
        out[1200 + img * 100 + tid] = 0.f;
    }
    __syncthreads();
    __shared__ float rv[256];
    __shared__ int ri[256];
    __shared__ float selbox[4];
    const float NEG = -__builtin_inff();
    for (int det = 0; det < 100; ++det) {
        float bv = NEG; int bi = -1;
        for (int j = tid; j < Vn; j += 256) {
            float s = sc[j];
            if (s > bv) { bv = s; bi = j; }
        }
        rv[tid] = bv; ri[tid] = bi;
        __syncthreads();
        for (int off = 128; off > 0; off >>= 1) {
            if (tid < off) {
                float ov = rv[tid + off]; int oi = ri[tid + off];
                if (ov > rv[tid] ||
                    (ov == rv[tid] && oi != -1 && (ri[tid] == -1 || oi < ri[tid]))) {
                    rv[tid] = ov; ri[tid] = oi;
                }
            }
            __syncthreads();
        }
        float mval = rv[0]; int mi = ri[0];
        if (!(mval > NEG) || mi < 0) break;
        if (tid == 0) {
            out[img * 400 + det * 4 + 0] = cb[mi * 4 + 0];
            out[img * 400 + det * 4 + 1] = cb[mi * 4 + 1];
            out[img * 400 + det * 4 + 2] = cb[mi * 4 + 2];
            out[img * 400 + det * 4 + 3] = cb[mi * 4 + 3];
            out[800 + img * 100 + det] = mval;
            out[1000 + img * 100 + det] = (float)cl[mi];
            out[1200 + img * 100 + det] = 1.0f;
            selbox[0] = cb[mi * 4 + 0]; selbox[1] = cb[mi * 4 + 1];
            selbox[2] = cb[mi * 4 + 2]; selbox[3] = cb[mi * 4 + 3];
            sc[mi] = NEG;
        }
        __syncthreads();
        float bx1 = selbox[0], by1 = selbox[1], bx2 = selbox[2], by2 = selbox[3];
        float a1 = (bx2 - bx1) * (by2 - by1);
        for (int j = tid; j < Vn; j += 256) {
            float s = sc[j];
            if (s == NEG) continue;
            float x1 = fmaxf(bx1, cb[j * 4 + 0]), y1 = fmaxf(by1, cb[j * 4 + 1]);
            float x2 = fminf(bx2, cb[j * 4 + 2]), y2 = fminf(by2, cb[j * 4 + 3]);
            float iw = fmaxf(x2 - x1, 0.f), ih = fmaxf(y2 - y1, 0.f);
            float inter = iw * ih;
            float a2 = (cb[j * 4 + 2] - cb[j * 4 + 0]) * (cb[j * 4 + 3] - cb[j * 4 + 1]);
            float iou = inter / (a1 + a2 - inter + 1e-9f);
            if (iou > 0.5f) sc[j] = NEG;
        }
        __syncthreads();
    }
}

extern "C" void kernel_launch(void* const* d_in, const int* in_sizes, int n_in,
                              void* d_out, int out_size, void* d_ws, size_t ws_size,
                              hipStream_t stream) {
    const float* features  = (const float*)d_in[0];
    const float* proposals = (const float*)d_in[1];
    const float* W1 = (const float*)d_in[2];
    const float* b1 = (const float*)d_in[3];
    const float* W2 = (const float*)d_in[4];
    const float* b2 = (const float*)d_in[5];
    const float* Wc = (const float*)d_in[6];
    const float* bc = (const float*)d_in[7];
    const float* Wb = (const float*)d_in[8];
    const float* bb = (const float*)d_in[9];

    // FC1 split-K tier by workspace (ws observed ~256MB)
    int zf1, kb1, kr1;
    if (ws_size >= 51380224UL + 8UL * 2097152UL + 3145728UL) { zf1 = 8; kb1 = 24; kr1 = 4; }
    else { zf1 = 4; kb1 = 49; kr1 = 0; }

    char* ws = (char*)d_ws;
    // phase A
    short* Xb    = (short*)(ws);                      // 25,690,112 B
    short* W1t   = (short*)(ws + 25690112);           // 25,690,112 B
    short* featT = (short*)(ws + 51380224);           // 2,560,000 B (dead before P written)
    short* P     = (short*)(ws + 51380224);           // [zf1][1024][1024] bf16
    short* W2t_e = (short*)(ws + 51380224 + (size_t)zf1 * 2097152);  // 2MB
    short* Wht_e = (short*)((char*)W2t_e + 2097152);                 // 1MB ([512][1024], rows 405+ unused)
    // phase B (reuses ex-Xb region after FC1)
    short* H1b   = (short*)(ws);                      // 2 MB
    short* H2b   = (short*)(ws + 5242880);            // 2 MB
    float* Obuf  = (float*)(ws + 7340032);            // [1024][448] f32
    float* Boxes = (float*)(ws + 9175040);
    float* Scores= (float*)(ws + 10485760);
    unsigned char* Valid = (unsigned char*)(ws + 10813440);
    float* CB    = (float*)(ws + 10895360);
    int*   CL    = (int*)(ws + 12206080);
    float* CSw   = (float*)(ws + 12533760);

    transpose_all<<<15280, 256, 0, stream>>>(W1, features, W2, Wc, Wb, W1t, featT, W2t_e, Wht_e);
    roi_align_v3<<<1024, 256, 0, stream>>>(featT, proposals, Xb);

    // FC1: X[1024,12544] @ W1t^T -> P partials -> H1 = relu(sum + b1)
    gemm64<0><<<dim3(16, 8, zf1), 256, 0, stream>>>(Xb, W1t, nullptr, nullptr, (void*)P,
                                                    1024, 1024, 12544, kb1, kr1);
    reduceN_relu<<<512, 256, 0, stream>>>(P, b1, H1b, zf1);

    // FC2: direct, bias+relu fused
    gemm64<1><<<dim3(16, 8, 1), 256, 0, stream>>>(H1b, W2t_e, b2, nullptr, (void*)H2b,
                                                  1024, 1024, 1024, 16, 0);
    // head: direct, N = 448 = 7*64 exactly, bias fused
    gemm64<2><<<dim3(7, 8, 1), 256, 0, stream>>>(H2b, Wht_e, bc, bb, (void*)Obuf,
                                                 1024, 448, 1024, 16, 0);

    head_epilogue<<<1024, 64, 0, stream>>>(Obuf, proposals, Boxes, Scores, Valid);
    nms_fused<<<2, 256, 0, stream>>>(Boxes, Scores, Valid, CB, CL, CSw, (float*)d_out);
}

// Round 10
// 136.515 us; speedup vs baseline: 1.0168x; 1.0168x over previous
//
#include <hip/hip_runtime.h>
#include <hip/hip_bf16.h>

typedef __attribute__((ext_vector_type(8))) short short8;
typedef __attribute__((ext_vector_type(4))) float f32x4;

__device__ inline short f2bf(float x) {
    union { __hip_bfloat16 b; short s; } u;
    u.b = __float2bfloat16(x);
    return u.s;
}
__device__ inline float bf2f(short s) {
    union { __hip_bfloat16 b; short s; } u;
    u.s = s;
    return __bfloat162float(u.b);
}

#define GLDS16(g, l) __builtin_amdgcn_global_load_lds( \
    (const __attribute__((address_space(1))) void*)(g), \
    (__attribute__((address_space(3))) void*)(l), 16, 0, 0)

// ---------------- merged transpose + f32->bf16 convert (all weights + features) ----
__global__ void transpose_all(const float* __restrict__ W1, const float* __restrict__ features,
                              const float* __restrict__ W2, const float* __restrict__ Wc,
                              const float* __restrict__ Wb,
                              short* __restrict__ W1t, short* __restrict__ featT,
                              short* __restrict__ W2t, short* __restrict__ Wht) {
    int id = blockIdx.x;
    const float* in;
    short* out;
    int R, C, r0, c0;
    if (id < 12544) {
        in = W1; out = W1t; R = 12544; C = 1024;
        r0 = (id % 392) * 32; c0 = (id / 392) * 32;
    } else if (id < 13808) {
        int f = id - 12544;
        int img = f / 632, g = f % 632;
        in = features + (long)img * 640000;
        out = featT + (long)img * 640000;
        R = 256; C = 2500;
        r0 = (g % 8) * 32; c0 = (g / 8) * 32;
    } else if (id < 14832) {
        int g = id - 13808;
        in = W2; out = W2t; R = 1024; C = 1024;
        r0 = (g % 32) * 32; c0 = (g / 32) * 32;
    } else if (id < 14928) {
        int g = id - 14832;
        in = Wc; out = Wht; R = 1024; C = 81;
        r0 = (g % 32) * 32; c0 = (g / 32) * 32;
    } else {
        int g = id - 14928;
        in = Wb; out = Wht + 81 * 1024; R = 1024; C = 324;
        r0 = (g % 32) * 32; c0 = (g / 32) * 32;
    }
    __shared__ float tile[32][33];
    int tr = threadIdx.x >> 5;
    int tc = threadIdx.x & 31;
    #pragma unroll
    for (int i = 0; i < 4; ++i) {
        int r = r0 + tr + i * 8;
        int c = c0 + tc;
        float v = 0.f;
        if (c < C) v = in[(long)r * C + c];
        tile[tr + i * 8][tc] = v;
    }
    __syncthreads();
    #pragma unroll
    for (int i = 0; i < 4; ++i) {
        int n = c0 + tr + i * 8;
        int k = r0 + tc;
        if (n < C) out[(long)n * R + k] = f2bf(tile[tc][tr + i * 8]);
    }
}

// ---------------- ROI-align v3: 16B vector loads, wave-half corner split ----------
__global__ __launch_bounds__(256) void roi_align_v3(const short* __restrict__ featT,
                                                    const float* __restrict__ props,
                                                    short* __restrict__ Xb) {
    int roi = blockIdx.x;
    int img = roi >> 9;
    __shared__ unsigned int soffB[784];
    __shared__ float swB[784];
    __shared__ float pbox[4];
    __shared__ short outb[49 * 264];
    int tid = threadIdx.x;
    if (tid < 4) pbox[tid] = props[roi * 4 + tid];
    __syncthreads();
    if (tid < 196) {
        float x1 = pbox[0] * 0.0625f, y1 = pbox[1] * 0.0625f;
        float x2 = pbox[2] * 0.0625f, y2 = pbox[3] * 0.0625f;
        float rw = fmaxf(x2 - x1, 1.0f), rh = fmaxf(y2 - y1, 1.0f);
        int p = tid >> 2, q = tid & 3;
        int py = p / 7, px = p % 7;
        int sy = q >> 1, sx = q & 1;
        int gy = py * 2 + sy, gx = px * 2 + sx;
        float gyv = ((float)gy + 0.5f) * 0.5f;
        float gxv = ((float)gx + 0.5f) * 0.5f;
        float ys = y1 + gyv * (rh * (1.0f / 7.0f));
        float xs = x1 + gxv * (rw * (1.0f / 7.0f));
        ys = fminf(fmaxf(ys, 0.0f), 49.0f);
        xs = fminf(fmaxf(xs, 0.0f), 49.0f);
        float y0f = floorf(ys), x0f = floorf(xs);
        int y0 = (int)y0f, x0 = (int)x0f;
        int y1i = min(y0 + 1, 49), x1i = min(x0 + 1, 49);
        float ly = ys - y0f, lx = xs - x0f;
        float hy = 1.f - ly, hx = 1.f - lx;
        int b00 = (y0 * 50 + x0) << 9;
        int ddx = (x1i - x0) << 9;
        int ddy = (y1i - y0) * 25600;
        int t4 = tid << 2;
        soffB[t4 + 0] = b00;             swB[t4 + 0] = hy * hx * 0.25f;
        soffB[t4 + 1] = b00 + ddx;       swB[t4 + 1] = hy * lx * 0.25f;
        soffB[t4 + 2] = b00 + ddy;       swB[t4 + 2] = ly * hx * 0.25f;
        soffB[t4 + 3] = b00 + ddy + ddx; swB[t4 + 3] = ly * lx * 0.25f;
    }
    __syncthreads();
    int w = tid >> 6, l = tid & 63;
    int half = l >> 5, ch16 = l & 31;
    const char* fbase = (const char*)featT + (long)img * 1280000 + (ch16 << 4);
    for (int p = w; p < 49; p += 4) {
        float acc[8] = {};
        #pragma unroll
        for (int ld = 0; ld < 8; ++ld) {
            int idx = (p << 4) + (ld << 1) + half;
            unsigned int off = soffB[idx];
            float wgt = swB[idx];
            short8 v = *(const short8*)(fbase + off);
            union { short8 s; unsigned int u[4]; } uv;
            uv.s = v;
            #pragma unroll
            for (int k2 = 0; k2 < 4; ++k2) {
                unsigned int u = uv.u[k2];
                float flo = __uint_as_float(u << 16);
                float fhi = __uint_as_float(u & 0xffff0000u);
                acc[k2 * 2]     += wgt * flo;
                acc[k2 * 2 + 1] += wgt * fhi;
            }
        }
        short8 o;
        #pragma unroll
        for (int j = 0; j < 8; ++j) {
            float t = acc[j] + __shfl_xor(acc[j], 32);
            o[j] = f2bf(t);
        }
        if (half == 0) *(short8*)&outb[p * 264 + (ch16 << 3)] = o;
    }
    __syncthreads();
    int c = tid / 49, r = tid % 49;
    short* xrow = Xb + (long)roi * 12544;
    #pragma unroll 1
    for (int i = 0; i < 49; ++i) {
        xrow[tid + i * 256] = outb[r * 264 + c];
        c += 5; r += 11;
        if (r >= 49) { r -= 49; c += 1; }
    }
}

// ---- FC1: 128x128, BK=64, SINGLE-buffer 32KB LDS (m97 structure), split-K partials ----
// P[z][M][N] = A[M,K-slice] @ Bt[N,K-slice]^T  (bf16 out, no bias)
__global__ __launch_bounds__(256) void gemm128s(const short* __restrict__ A,
                                                const short* __restrict__ Bt,
                                                short* __restrict__ Cout,
                                                int M, int N, int K, int kbase, int krem) {
    __shared__ short As[128 * 64];   // 16KB
    __shared__ short Bs[128 * 64];   // 16KB -> 32KB total, 4+ blocks/CU
    int gx = gridDim.x, gy = gridDim.y;
    int nwg = gx * gy * gridDim.z;
    int orig = blockIdx.x + gx * (blockIdx.y + gy * blockIdx.z);
    int wg = orig;
    if ((nwg & 7) == 0 && nwg >= 64) {
        int q = nwg >> 3;
        wg = (orig & 7) * q + (orig >> 3);
    }
    int bx_ = wg % gx;
    int tmp = wg / gx;
    int by_ = tmp % gy;
    int bz_ = tmp / gy;
    int ksteps = kbase + (bz_ < krem ? 1 : 0);
    long kbeg = ((long)bz_ * kbase + (bz_ < krem ? bz_ : krem)) * 64;
    int m0 = by_ * 128, n0 = bx_ * 128;
    int tid = threadIdx.x;
    int w = tid >> 6, lane = tid & 63;
    int wr = w >> 1, wc = w & 1;
    int lr = lane & 15, lk = lane >> 4;
    int srow = tid >> 3;
    int sbx = ((tid & 7) ^ (srow & 7)) << 4;
    const char* Ag = (const char*)A + ((long)(m0 + srow) * K + kbeg) * 2 + sbx;
    const char* Bg = (const char*)Bt + ((long)(n0 + srow) * K + kbeg) * 2 + sbx;
    const long rstep = (long)K * 64;
    char* As0 = (char*)&As[0];
    char* Bs0 = (char*)&Bs[0];
    int wofs = w << 10;
    int sw = (lr & 7) << 4;
    f32x4 acc[4][4] = {};

    for (int t = 0; t < ksteps; ++t) {
        const char* a = Ag + (long)t * 128;
        const char* b = Bg + (long)t * 128;
        #pragma unroll
        for (int i = 0; i < 4; ++i) {
            GLDS16(a + i * rstep, As0 + wofs + i * 4096);
            GLDS16(b + i * rstep, Bs0 + wofs + i * 4096);
        }
        __syncthreads();   // drain glds, publish buffer
        #pragma unroll
        for (int kk = 0; kk < 2; ++kk) {
            short8 av[4], bv[4];
            #pragma unroll
            for (int f = 0; f < 4; ++f) {
                av[f] = *(const short8*)(As0 + (wr * 64 + f * 16 + lr) * 128 + ((kk * 64 + lk * 16) ^ sw));
                bv[f] = *(const short8*)(Bs0 + (wc * 64 + f * 16 + lr) * 128 + ((kk * 64 + lk * 16) ^ sw));
            }
            #pragma unroll
            for (int fm = 0; fm < 4; ++fm)
                #pragma unroll
                for (int fn = 0; fn < 4; ++fn)
                    acc[fm][fn] = __builtin_amdgcn_mfma_f32_16x16x32_bf16(av[fm], bv[fn], acc[fm][fn], 0, 0, 0);
        }
        __syncthreads();   // protect buffer before next stage
    }
    #pragma unroll
    for (int fm = 0; fm < 4; ++fm) {
        #pragma unroll
        for (int fn = 0; fn < 4; ++fn) {
            int col = n0 + wc * 64 + fn * 16 + lr;
            #pragma unroll
            for (int j = 0; j < 4; ++j) {
                int row = m0 + wr * 64 + fm * 16 + lk * 4 + j;
                Cout[(long)bz_ * M * N + (long)row * N + col] = f2bf(acc[fm][fn][j]);
            }
        }
    }
}

// ---- FC2/head: 128x128, BK=128, double-buffered (128KB LDS; grids are <=64 blocks,
//      so 1 block/CU is not a constraint — halves the serial k-chain) ----
// MODE 1: bias+relu -> bf16; MODE 2: (bc|bb|0) bias -> f32, store col < Ncap
template <int MODE>
__global__ __launch_bounds__(256) void gemm128w(const short* __restrict__ A,
                                                const short* __restrict__ Bt,
                                                const float* __restrict__ bias,
                                                const float* __restrict__ bias2,
                                                void* __restrict__ Cout,
                                                int M, int N, int K, int Ncap) {
    __shared__ short As[2][128 * 128];   // 2 x 32KB
    __shared__ short Bs[2][128 * 128];   // 2 x 32KB -> 128KB
    int bx_ = blockIdx.x, by_ = blockIdx.y;
    int m0 = by_ * 128, n0 = bx_ * 128;
    int ksteps = K >> 7;                 // BK = 128
    int tid = threadIdx.x;
    int w = tid >> 6, lane = tid & 63;
    int wr = w >> 1, wc = w & 1;
    int lr = lane & 15, lk = lane >> 4;
    int srow = tid >> 4;                 // 0..15 (16 rows/pass, 8 passes)
    int scol = tid & 15;
    int sbx = ((scol ^ (srow & 7)) << 4);
    const char* Ag = (const char*)A + ((long)(m0 + srow) * K) * 2 + sbx;
    const char* Bg = (const char*)Bt + ((long)(n0 + srow) * K) * 2 + sbx;
    const long rstep = (long)K << 5;     // 16 rows * K * 2B
    char* As0 = (char*)&As[0][0];
    char* Bs0 = (char*)&Bs[0][0];
    f32x4 acc[4][4] = {};

    #define STAGEW(t, b) do { \
        const char* _a = Ag + (long)(t) * 256; \
        const char* _b = Bg + (long)(t) * 256; \
        char* _ad = As0 + ((b) << 15) + tid * 16; \
        char* _bd = Bs0 + ((b) << 15) + tid * 16; \
        _Pragma("unroll") \
        for (int _i = 0; _i < 8; ++_i) { \
            GLDS16(_a + _i * rstep, _ad + _i * 4096); \
            GLDS16(_b + _i * rstep, _bd + _i * 4096); \
        } \
    } while (0)

    STAGEW(0, 0);
    __syncthreads();
    int cur = 0;
    for (int t = 0; t < ksteps; ++t) {
        if (t + 1 < ksteps) STAGEW(t + 1, cur ^ 1);
        const char* as = As0 + (cur << 15);
        const char* bs = Bs0 + (cur << 15);
        #pragma unroll
        for (int kk = 0; kk < 4; ++kk) {
            short8 av[4], bv[4];
            #pragma unroll
            for (int f = 0; f < 4; ++f) {
                int ra = wr * 64 + f * 16 + lr;
                int rb = wc * 64 + f * 16 + lr;
                int ch = kk * 4 + lk;
                av[f] = *(const short8*)(as + ra * 256 + ((ch ^ (ra & 7)) << 4));
                bv[f] = *(const short8*)(bs + rb * 256 + ((ch ^ (rb & 7)) << 4));
            }
            #pragma unroll
            for (int fm = 0; fm < 4; ++fm)
                #pragma unroll
                for (int fn = 0; fn < 4; ++fn)
                    acc[fm][fn] = __builtin_amdgcn_mfma_f32_16x16x32_bf16(av[fm], bv[fn], acc[fm][fn], 0, 0, 0);
        }
        __syncthreads();
        cur ^= 1;
    }
    #undef STAGEW

    #pragma unroll
    for (int fm = 0; fm < 4; ++fm) {
        #pragma unroll
        for (int fn = 0; fn < 4; ++fn) {
            int col = n0 + wc * 64 + fn * 16 + lr;
            float bv = 0.f;
            if (MODE == 1) bv = bias[col];
            if (MODE == 2) bv = (col < 81) ? bias[col] : (col < 405 ? bias2[col - 81] : 0.f);
            #pragma unroll
            for (int j = 0; j < 4; ++j) {
                int row = m0 + wr * 64 + fm * 16 + lk * 4 + j;
                float v = acc[fm][fn][j];
                if (MODE == 1) {
                    ((short*)Cout)[(long)row * N + col] = f2bf(fmaxf(v + bv, 0.f));
                } else {
                    if (col < Ncap) ((float*)Cout)[(long)row * Ncap + col] = v + bv;
                }
            }
        }
    }
}

// ---------------- split-K reduce: H1 = relu(sum_s P[s] + b1) -> bf16 ----------------
__global__ void reduceN_relu(const short* __restrict__ P, const float* __restrict__ bias,
                             short* __restrict__ Hout, int nsl) {
    long i0 = ((long)blockIdx.x * 256 + threadIdx.x) * 8;
    int col = (int)(i0 & 1023);
    float v[8];
    #pragma unroll
    for (int j = 0; j < 8; ++j) v[j] = bias[col + j];
    for (int s = 0; s < nsl; ++s) {
        short8 p = *(const short8*)(P + (long)s * 1048576 + i0);
        #pragma unroll
        for (int j = 0; j < 8; ++j) v[j] += bf2f(p[j]);
    }
    short8 o;
    #pragma unroll
    for (int j = 0; j < 8; ++j) o[j] = f2bf(fmaxf(v[j], 0.f));
    *(short8*)(Hout + i0) = o;
}

// ---------------- softmax + decode + valid ----------------
__global__ void head_epilogue(const float* __restrict__ O,      // [1024][448]
                              const float* __restrict__ props,
                              float* __restrict__ Boxes,
                              float* __restrict__ Scores,
                              unsigned char* __restrict__ Valid) {
    int roi = blockIdx.x;
    int lane = threadIdx.x;  // 64
    const float* o = O + (long)roi * 448;
    float m = -1e30f;
    for (int i = lane; i < 81; i += 64) m = fmaxf(m, o[i]);
    for (int off = 32; off > 0; off >>= 1) m = fmaxf(m, __shfl_xor(m, off));
    float ssum = 0.f;
    for (int i = lane; i < 81; i += 64) ssum += expf(o[i] - m);
    for (int off = 32; off > 0; off >>= 1) ssum += __shfl_xor(ssum, off);
    float inv = 1.0f / ssum;
    int img = roi >> 9, rb = roi & 511;
    float px1 = props[roi * 4 + 0], py1 = props[roi * 4 + 1];
    float px2 = props[roi * 4 + 2], py2 = props[roi * 4 + 3];
    float w = px2 - px1, h = py2 - py1;
    float cx = px1 + 0.5f * w, cy = py1 + 0.5f * h;
    long obase = (long)img * 40960 + (long)rb * 80;
    const float DW = 4.135166556742356f;
    for (int t = lane; t < 80; t += 64) {
        int cls = t + 1;
        float score = expf(o[cls] - m) * inv;
        const float* d = o + 81 + cls * 4;
        float dx = d[0] * 0.1f, dy = d[1] * 0.1f;
        float dw = fminf(d[2] * 0.2f, DW);
        float dh = fminf(d[3] * 0.2f, DW);
        float pcx = dx * w + cx, pcy = dy * h + cy;
        float pw = expf(dw) * w, ph = expf(dh) * h;
        float x1 = pcx - 0.5f * pw, y1 = pcy - 0.5f * ph;
        float x2 = pcx + 0.5f * pw, y2 = pcy + 0.5f * ph;
        x1 = fminf(fmaxf(x1, 0.f), 800.f); y1 = fminf(fmaxf(y1, 0.f), 800.f);
        x2 = fminf(fmaxf(x2, 0.f), 800.f); y2 = fminf(fmaxf(y2, 0.f), 800.f);
        float wv = x2 - x1, hv = y2 - y1;
        long oi = obase + t;
        Boxes[oi * 4 + 0] = x1; Boxes[oi * 4 + 1] = y1;
        Boxes[oi * 4 + 2] = x2; Boxes[oi * 4 + 3] = y2;
        Scores[oi] = score;
        Valid[oi] = (score >= 0.05f && wv >= 1.0f && hv >= 1.0f) ? 1 : 0;
    }
}

// ---------------- fused compaction + greedy NMS (one block per image) ----------------
__global__ void nms_fused(const float* __restrict__ Boxes, const float* __restrict__ Scores,
                          const unsigned char* __restrict__ Valid,
                          float* __restrict__ CB, int* __restrict__ CL,
                          float* __restrict__ CSw, float* __restrict__ out) {
    int img = blockIdx.x;
    int tid = threadIdx.x;  // 256
    const int SEG = 160;
    const unsigned char* V = Valid + (long)img * 40960;
    int j0 = tid * SEG;
    const unsigned int* V4 = (const unsigned int*)(V + j0);
    int c = 0;
    #pragma unroll
    for (int k = 0; k < 40; ++k) {
        unsigned int u = V4[k];
        c += (int)((u * 0x01010101u) >> 24);
    }
    __shared__ int cnt[256];
    cnt[tid] = c;
    __syncthreads();
    for (int d = 1; d < 256; d <<= 1) {
        int v = (tid >= d) ? cnt[tid - d] : 0;
        __syncthreads();
        cnt[tid] += v;
        __syncthreads();
    }
    int pos = cnt[tid] - c;
    const float* B = Boxes + (long)img * 40960 * 4;
    const float* S = Scores + (long)img * 40960;
    float* cb = CB + (long)img * 40960 * 4;
    float* sc = CSw + (long)img * 40960;
    int* cl = CL + (long)img * 40960;
    if (c > 0) {
        for (int k = 0; k < SEG; ++k) {
            int j = j0 + k;
            if (V[j]) {
                sc[pos] = S[j];
                cb[pos * 4 + 0] = B[j * 4 + 0]; cb[pos * 4 + 1] = B[j * 4 + 1];
                cb[pos * 4 + 2] = B[j * 4 + 2]; cb[pos * 4 + 3] = B[j * 4 + 3];
                cl[pos] = (j % 80) + 1;
                ++pos;
            }
        }
    }
    int Vn = cnt[255];
    for (int i = tid; i < 400; i += 256) out[img * 400 + i] = 0.f;
    if (tid < 100) {
        out[800 + img * 100 + tid] = 0.f;
        out[1000 + img * 100 + tid] = 0.f;
        out[1200 + img * 100 + tid] = 0.f;
    }
    __syncthreads();
    __shared__ float rv[256];
    __shared__ int ri[256];
    __shared__ float selbox[4];
    const float NEG = -__builtin_inff();
    for (int det = 0; det < 100; ++det) {
        float bv = NEG; int bi = -1;
        for (int j = tid; j < Vn; j += 256) {
            float s = sc[j];
            if (s > bv) { bv = s; bi = j; }
        }
        rv[tid] = bv; ri[tid] = bi;
        __syncthreads();
        for (int off = 128; off > 0; off >>= 1) {
            if (tid < off) {
                float ov = rv[tid + off]; int oi = ri[tid + off];
                if (ov > rv[tid] ||
                    (ov == rv[tid] && oi != -1 && (ri[tid] == -1 || oi < ri[tid]))) {
                    rv[tid] = ov; ri[tid] = oi;
                }
            }
            __syncthreads();
        }
        float mval = rv[0]; int mi = ri[0];
        if (!(mval > NEG) || mi < 0) break;
        if (tid == 0) {
            out[img * 400 + det * 4 + 0] = cb[mi * 4 + 0];
            out[img * 400 + det * 4 + 1] = cb[mi * 4 + 1];
            out[img * 400 + det * 4 + 2] = cb[mi * 4 + 2];
            out[img * 400 + det * 4 + 3] = cb[mi * 4 + 3];
            out[800 + img * 100 + det] = mval;
            out[1000 + img * 100 + det] = (float)cl[mi];
            out[1200 + img * 100 + det] = 1.0f;
            selbox[0] = cb[mi * 4 + 0]; selbox[1] = cb[mi * 4 + 1];
            selbox[2] = cb[mi * 4 + 2]; selbox[3] = cb[mi * 4 + 3];
            sc[mi] = NEG;
        }
        __syncthreads();
        float bx1 = selbox[0], by1 = selbox[1], bx2 = selbox[2], by2 = selbox[3];
        float a1 = (bx2 - bx1) * (by2 - by1);
        for (int j = tid; j < Vn; j += 256) {
            float s = sc[j];
            if (s == NEG) continue;
            float x1 = fmaxf(bx1, cb[j * 4 + 0]), y1 = fmaxf(by1, cb[j * 4 + 1]);
            float x2 = fminf(bx2, cb[j * 4 + 2]), y2 = fminf(by2, cb[j * 4 + 3]);
            float iw = fmaxf(x2 - x1, 0.f), ih = fmaxf(y2 - y1, 0.f);
            float inter = iw * ih;
            float a2 = (cb[j * 4 + 2] - cb[j * 4 + 0]) * (cb[j * 4 + 3] - cb[j * 4 + 1]);
            float iou = inter / (a1 + a2 - inter + 1e-9f);
            if (iou > 0.5f) sc[j] = NEG;
        }
        __syncthreads();
    }
}

extern "C" void kernel_launch(void* const* d_in, const int* in_sizes, int n_in,
                              void* d_out, int out_size, void* d_ws, size_t ws_size,
                              hipStream_t stream) {
    const float* features  = (const float*)d_in[0];
    const float* proposals = (const float*)d_in[1];
    const float* W1 = (const float*)d_in[2];
    const float* b1 = (const float*)d_in[3];
    const float* W2 = (const float*)d_in[4];
    const float* b2 = (const float*)d_in[5];
    const float* Wc = (const float*)d_in[6];
    const float* bc = (const float*)d_in[7];
    const float* Wb = (const float*)d_in[8];
    const float* bb = (const float*)d_in[9];

    // FC1 split-K tier by workspace (ws observed ~256MB)
    int zf1, kb1, kr1;
    if (ws_size >= 51380224UL + 16UL * 2097152UL + 3145728UL) { zf1 = 16; kb1 = 12; kr1 = 4; }
    else if (ws_size >= 51380224UL + 8UL * 2097152UL + 3145728UL) { zf1 = 8; kb1 = 24; kr1 = 4; }
    else { zf1 = 4; kb1 = 49; kr1 = 0; }

    char* ws = (char*)d_ws;
    // phase A
    short* Xb    = (short*)(ws);                      // 25,690,112 B
    short* W1t   = (short*)(ws + 25690112);           // 25,690,112 B
    short* featT = (short*)(ws + 51380224);           // 2,560,000 B (dead before P written)
    short* P     = (short*)(ws + 51380224);           // [zf1][1024][1024] bf16
    short* W2t_e = (short*)(ws + 51380224 + (size_t)zf1 * 2097152);  // 2MB
    short* Wht_e = (short*)((char*)W2t_e + 2097152);                 // 1MB ([512][1024], rows 405+ unused)
    // phase B (reuses ex-Xb region after FC1)
    short* H1b   = (short*)(ws);                      // 2 MB
    short* H2b   = (short*)(ws + 5242880);            // 2 MB
    float* Obuf  = (float*)(ws + 7340032);            // [1024][448] f32
    float* Boxes = (float*)(ws + 9175040);
    float* Scores= (float*)(ws + 10485760);
    unsigned char* Valid = (unsigned char*)(ws + 10813440);
    float* CB    = (float*)(ws + 10895360);
    int*   CL    = (int*)(ws + 12206080);
    float* CSw   = (float*)(ws + 12533760);

    transpose_all<<<15280, 256, 0, stream>>>(W1, features, W2, Wc, Wb, W1t, featT, W2t_e, Wht_e);
    roi_align_v3<<<1024, 256, 0, stream>>>(featT, proposals, Xb);

    // FC1: single-buffer m97-structure, z=16 -> 4 blocks/CU
    gemm128s<<<dim3(8, 8, zf1), 256, 0, stream>>>(Xb, W1t, P, 1024, 1024, 12544, kb1, kr1);
    reduceN_relu<<<512, 256, 0, stream>>>(P, b1, H1b, zf1);

    // FC2: BK=128 dbuf direct (8 k-steps), bias+relu fused
    gemm128w<1><<<dim3(8, 8), 256, 0, stream>>>(H1b, W2t_e, b2, nullptr, (void*)H2b,
                                                1024, 1024, 1024, 1024);
    // head: BK=128 dbuf direct, N=512 tiles w/ col<448 guard, bias fused
    gemm128w<2><<<dim3(4, 8), 256, 0, stream>>>(H2b, Wht_e, bc, bb, (void*)Obuf,
                                                1024, 512, 1024, 448);

    head_epilogue<<<1024, 64, 0, stream>>>(Obuf, proposals, Boxes, Scores, Valid);
    nms_fused<<<2, 256, 0, stream>>>(Boxes, Scores, Valid, CB, CL, CSw, (float*)d_out);
}

// Round 11
// 132.403 us; speedup vs baseline: 1.0484x; 1.0311x over previous
//
#include <hip/hip_runtime.h>
#include <hip/hip_bf16.h>

typedef __attribute__((ext_vector_type(8))) short short8;
typedef __attribute__((ext_vector_type(4))) float f32x4;

__device__ inline short f2bf(float x) {
    union { __hip_bfloat16 b; short s; } u;
    u.b = __float2bfloat16(x);
    return u.s;
}
__device__ inline float bf2f(short s) {
    union { __hip_bfloat16 b; short s; } u;
    u.s = s;
    return __bfloat162float(u.b);
}

#define GLDS16(g, l) __builtin_amdgcn_global_load_lds( \
    (const __attribute__((address_space(1))) void*)(g), \
    (__attribute__((address_space(3))) void*)(l), 16, 0, 0)

// ---------------- features -> channel-last bf16 (must precede roi) ----------------
__global__ void featT_cvt(const float* __restrict__ features, short* __restrict__ featT) {
    const float* in = features + (long)blockIdx.z * 640000;   // [256][2500]
    short* out = featT + (long)blockIdx.z * 640000;           // [2500][256]
    __shared__ float tile[32][33];
    int r0 = blockIdx.x * 32;       // row (channel), 8 blocks
    int c0 = blockIdx.y * 32;       // col (position), 79 blocks
    int tr = threadIdx.x >> 5;
    int tc = threadIdx.x & 31;
    #pragma unroll
    for (int i = 0; i < 4; ++i) {
        int r = r0 + tr + i * 8;
        int c = c0 + tc;
        float v = 0.f;
        if (c < 2500) v = in[(long)r * 2500 + c];
        tile[tr + i * 8][tc] = v;
    }
    __syncthreads();
    #pragma unroll
    for (int i = 0; i < 4; ++i) {
        int n = c0 + tr + i * 8;    // position
        int k = r0 + tc;            // channel
        if (n < 2500) out[(long)n * 256 + k] = f2bf(tile[tc][tr + i * 8]);
    }
}

// ------- merged: ROI-align (VALU-bound) || weight transposes (BW-bound) -------
// block id: [0,1024) roi | [1024,13568) W1 | [13568,14592) W2 | [14592,14688) Wc
//           | [14688,15040) Wb.  Independent jobs -> co-scheduled, pipes overlap.
__global__ __launch_bounds__(256) void prep_roi(const float* __restrict__ W1,
                                                const float* __restrict__ W2,
                                                const float* __restrict__ Wc,
                                                const float* __restrict__ Wb,
                                                const short* __restrict__ featT,
                                                const float* __restrict__ props,
                                                short* __restrict__ W1t,
                                                short* __restrict__ W2t,
                                                short* __restrict__ Wht,
                                                short* __restrict__ Xb) {
    __shared__ __align__(16) char shbuf[32160];
    int id = blockIdx.x;
    int tid = threadIdx.x;

    if (id >= 1024) {
        // ---- transpose job ----
        const float* in;
        short* out;
        int R, C, r0, c0;
        if (id < 13568) {
            int g = id - 1024;
            in = W1; out = W1t; R = 12544; C = 1024;
            r0 = (g % 392) * 32; c0 = (g / 392) * 32;
        } else if (id < 14592) {
            int g = id - 13568;
            in = W2; out = W2t; R = 1024; C = 1024;
            r0 = (g % 32) * 32; c0 = (g / 32) * 32;
        } else if (id < 14688) {
            int g = id - 14592;
            in = Wc; out = Wht; R = 1024; C = 81;
            r0 = (g % 32) * 32; c0 = (g / 32) * 32;
        } else {
            int g = id - 14688;
            in = Wb; out = Wht + 81 * 1024; R = 1024; C = 324;
            r0 = (g % 32) * 32; c0 = (g / 32) * 32;
        }
        float (*tile)[33] = (float(*)[33])shbuf;
        int tr = tid >> 5, tc = tid & 31;
        #pragma unroll
        for (int i = 0; i < 4; ++i) {
            int r = r0 + tr + i * 8;
            int c = c0 + tc;
            float v = 0.f;
            if (c < C) v = in[(long)r * C + c];
            tile[tr + i * 8][tc] = v;
        }
        __syncthreads();
        #pragma unroll
        for (int i = 0; i < 4; ++i) {
            int n = c0 + tr + i * 8;
            int k = r0 + tc;
            if (n < C) out[(long)n * R + k] = f2bf(tile[tc][tr + i * 8]);
        }
        return;
    }

    // ---- roi-align job ----
    int roi = id;
    int img = roi >> 9;
    unsigned int* soffB = (unsigned int*)shbuf;          // 784
    float* swB  = (float*)(shbuf + 3136);                // 784
    float* pbox = (float*)(shbuf + 6272);                // 4
    short* outb = (short*)(shbuf + 6288);                // 49*264
    if (tid < 4) pbox[tid] = props[roi * 4 + tid];
    __syncthreads();
    if (tid < 196) {
        float x1 = pbox[0] * 0.0625f, y1 = pbox[1] * 0.0625f;
        float x2 = pbox[2] * 0.0625f, y2 = pbox[3] * 0.0625f;
        float rw = fmaxf(x2 - x1, 1.0f), rh = fmaxf(y2 - y1, 1.0f);
        int p = tid >> 2, q = tid & 3;
        int py = p / 7, px = p % 7;
        int sy = q >> 1, sx = q & 1;
        int gy = py * 2 + sy, gx = px * 2 + sx;
        float gyv = ((float)gy + 0.5f) * 0.5f;
        float gxv = ((float)gx + 0.5f) * 0.5f;
        float ys = y1 + gyv * (rh * (1.0f / 7.0f));
        float xs = x1 + gxv * (rw * (1.0f / 7.0f));
        ys = fminf(fmaxf(ys, 0.0f), 49.0f);
        xs = fminf(fmaxf(xs, 0.0f), 49.0f);
        float y0f = floorf(ys), x0f = floorf(xs);
        int y0 = (int)y0f, x0 = (int)x0f;
        int y1i = min(y0 + 1, 49), x1i = min(x0 + 1, 49);
        float ly = ys - y0f, lx = xs - x0f;
        float hy = 1.f - ly, hx = 1.f - lx;
        int b00 = (y0 * 50 + x0) << 9;
        int ddx = (x1i - x0) << 9;
        int ddy = (y1i - y0) * 25600;
        int t4 = tid << 2;
        soffB[t4 + 0] = b00;             swB[t4 + 0] = hy * hx * 0.25f;
        soffB[t4 + 1] = b00 + ddx;       swB[t4 + 1] = hy * lx * 0.25f;
        soffB[t4 + 2] = b00 + ddy;       swB[t4 + 2] = ly * hx * 0.25f;
        soffB[t4 + 3] = b00 + ddy + ddx; swB[t4 + 3] = ly * lx * 0.25f;
    }
    __syncthreads();
    int w = tid >> 6, l = tid & 63;
    int half = l >> 5, ch16 = l & 31;
    const char* fbase = (const char*)featT + (long)img * 1280000 + (ch16 << 4);
    for (int p = w; p < 49; p += 4) {
        float acc[8] = {};
        #pragma unroll
        for (int ld = 0; ld < 8; ++ld) {
            int idx = (p << 4) + (ld << 1) + half;
            unsigned int off = soffB[idx];
            float wgt = swB[idx];
            short8 v = *(const short8*)(fbase + off);
            union { short8 s; unsigned int u[4]; } uv;
            uv.s = v;
            #pragma unroll
            for (int k2 = 0; k2 < 4; ++k2) {
                unsigned int u = uv.u[k2];
                float flo = __uint_as_float(u << 16);
                float fhi = __uint_as_float(u & 0xffff0000u);
                acc[k2 * 2]     += wgt * flo;
                acc[k2 * 2 + 1] += wgt * fhi;
            }
        }
        short8 o;
        #pragma unroll
        for (int j = 0; j < 8; ++j) {
            float t = acc[j] + __shfl_xor(acc[j], 32);
            o[j] = f2bf(t);
        }
        if (half == 0) *(short8*)&outb[p * 264 + (ch16 << 3)] = o;
    }
    __syncthreads();
    int c = tid / 49, r = tid % 49;
    short* xrow = Xb + (long)roi * 12544;
    #pragma unroll 1
    for (int i = 0; i < 49; ++i) {
        xrow[tid + i * 256] = outb[r * 264 + c];
        c += 5; r += 11;
        if (r >= 49) { r -= 49; c += 1; }
    }
}

// ---------------- 128x128 MFMA GEMM, glds + XOR swizzle + dbuf 2-phase ----------------
// (r7/r8-proven structure; bijective XCD-chunk remap)
// MODE 0: partial -> bf16 at Cout + z*M*N; MODE 1: bias+relu -> bf16; MODE 2: bias -> f32
template <int MODE>
__global__ __launch_bounds__(256) void gemm128(const short* __restrict__ A,
                                               const short* __restrict__ Bt,
                                               const float* __restrict__ bias,
                                               const float* __restrict__ bias2,
                                               void* __restrict__ Cout,
                                               int M, int N, int K, int kbase, int krem,
                                               int Ncap) {
    __shared__ short As[2][128 * 64];
    __shared__ short Bs[2][128 * 64];
    int gx = gridDim.x, gy = gridDim.y;
    int nwg = gx * gy * gridDim.z;
    int orig = blockIdx.x + gx * (blockIdx.y + gy * blockIdx.z);
    int wg = orig;
    if ((nwg & 7) == 0 && nwg >= 64) {
        int q = nwg >> 3;
        wg = (orig & 7) * q + (orig >> 3);
    }
    int bx_ = wg % gx;
    int tmp = wg / gx;
    int by_ = tmp % gy;
    int bz_ = tmp / gy;
    int ksteps = kbase + (bz_ < krem ? 1 : 0);
    long kbeg = ((long)bz_ * kbase + (bz_ < krem ? bz_ : krem)) * 64;
    int m0 = by_ * 128, n0 = bx_ * 128;
    int tid = threadIdx.x;
    int w = tid >> 6, lane = tid & 63;
    int wr = w >> 1, wc = w & 1;
    int lr = lane & 15, lk = lane >> 4;
    int srow = tid >> 3;
    int sbx = ((tid & 7) ^ (srow & 7)) << 4;
    const char* Ag = (const char*)A + ((long)(m0 + srow) * K + kbeg) * 2 + sbx;
    const char* Bg = (const char*)Bt + ((long)(n0 + srow) * K + kbeg) * 2 + sbx;
    const long rstep = (long)K * 64;
    char* As0 = (char*)&As[0][0];
    char* Bs0 = (char*)&Bs[0][0];
    int wofs = w << 10;
    int sw = (lr & 7) << 4;
    f32x4 acc[4][4] = {};

    #pragma unroll
    for (int i = 0; i < 4; ++i) {
        GLDS16(Ag + i * rstep, As0 + wofs + i * 4096);
        GLDS16(Bg + i * rstep, Bs0 + wofs + i * 4096);
    }
    __syncthreads();
    int cur = 0;
    for (int t = 0; t < ksteps; ++t) {
        if (t + 1 < ksteps) {
            const char* a = Ag + (long)(t + 1) * 128;
            const char* b = Bg + (long)(t + 1) * 128;
            char* ad = As0 + ((cur ^ 1) << 14) + wofs;
            char* bd = Bs0 + ((cur ^ 1) << 14) + wofs;
            #pragma unroll
            for (int i = 0; i < 4; ++i) {
                GLDS16(a + i * rstep, ad + i * 4096);
                GLDS16(b + i * rstep, bd + i * 4096);
            }
        }
        const char* as = As0 + (cur << 14);
        const char* bs = Bs0 + (cur << 14);
        #pragma unroll
        for (int kk = 0; kk < 2; ++kk) {
            short8 av[4], bv[4];
            #pragma unroll
            for (int f = 0; f < 4; ++f) {
                av[f] = *(const short8*)(as + (wr * 64 + f * 16 + lr) * 128 + ((kk * 64 + lk * 16) ^ sw));
                bv[f] = *(const short8*)(bs + (wc * 64 + f * 16 + lr) * 128 + ((kk * 64 + lk * 16) ^ sw));
            }
            #pragma unroll
            for (int fm = 0; fm < 4; ++fm)
                #pragma unroll
                for (int fn = 0; fn < 4; ++fn)
                    acc[fm][fn] = __builtin_amdgcn_mfma_f32_16x16x32_bf16(av[fm], bv[fn], acc[fm][fn], 0, 0, 0);
        }
        __syncthreads();
        cur ^= 1;
    }
    #pragma unroll
    for (int fm = 0; fm < 4; ++fm) {
        #pragma unroll
        for (int fn = 0; fn < 4; ++fn) {
            int col = n0 + wc * 64 + fn * 16 + lr;
            float bv = 0.f;
            if (MODE == 1) bv = bias[col];
            if (MODE == 2) bv = (col < 81) ? bias[col] : (col < 405 ? bias2[col - 81] : 0.f);
            #pragma unroll
            for (int j = 0; j < 4; ++j) {
                int row = m0 + wr * 64 + fm * 16 + lk * 4 + j;
                float v = acc[fm][fn][j];
                if (MODE == 0) {
                    ((short*)Cout)[(long)bz_ * M * N + (long)row * N + col] = f2bf(v);
                } else if (MODE == 1) {
                    ((short*)Cout)[(long)row * N + col] = f2bf(fmaxf(v + bv, 0.f));
                } else {
                    if (col < Ncap) ((float*)Cout)[(long)row * N + col] = v + bv;
                }
            }
        }
    }
}

// ---------------- split-K reduce: H1 = relu(sum_s P[s] + b1) -> bf16 ----------------
__global__ void reduceN_relu(const short* __restrict__ P, const float* __restrict__ bias,
                             short* __restrict__ Hout, int nsl) {
    long i0 = ((long)blockIdx.x * 256 + threadIdx.x) * 8;
    int col = (int)(i0 & 1023);
    float v[8];
    #pragma unroll
    for (int j = 0; j < 8; ++j) v[j] = bias[col + j];
    for (int s = 0; s < nsl; ++s) {
        short8 p = *(const short8*)(P + (long)s * 1048576 + i0);
        #pragma unroll
        for (int j = 0; j < 8; ++j) v[j] += bf2f(p[j]);
    }
    short8 o;
    #pragma unroll
    for (int j = 0; j < 8; ++j) o[j] = f2bf(fmaxf(v[j], 0.f));
    *(short8*)(Hout + i0) = o;
}

// ---------------- softmax + decode + valid ----------------
__global__ void head_epilogue(const float* __restrict__ O,      // [1024][448]
                              const float* __restrict__ props,
                              float* __restrict__ Boxes,
                              float* __restrict__ Scores,
                              unsigned char* __restrict__ Valid) {
    int roi = blockIdx.x;
    int lane = threadIdx.x;  // 64
    const float* o = O + (long)roi * 448;
    float m = -1e30f;
    for (int i = lane; i < 81; i += 64) m = fmaxf(m, o[i]);
    for (int off = 32; off > 0; off >>= 1) m = fmaxf(m, __shfl_xor(m, off));
    float ssum = 0.f;
    for (int i = lane; i < 81; i += 64) ssum += expf(o[i] - m);
    for (int off = 32; off > 0; off >>= 1) ssum += __shfl_xor(ssum, off);
    float inv = 1.0f / ssum;
    int img = roi >> 9, rb = roi & 511;
    float px1 = props[roi * 4 + 0], py1 = props[roi * 4 + 1];
    float px2 = props[roi * 4 + 2], py2 = props[roi * 4 + 3];
    float w = px2 - px1, h = py2 - py1;
    float cx = px1 + 0.5f * w, cy = py1 + 0.5f * h;
    long obase = (long)img * 40960 + (long)rb * 80;
    const float DW = 4.135166556742356f;
    for (int t = lane; t < 80; t += 64) {
        int cls = t + 1;
        float score = expf(o[cls] - m) * inv;
        const float* d = o + 81 + cls * 4;
        float dx = d[0] * 0.1f, dy = d[1] * 0.1f;
        float dw = fminf(d[2] * 0.2f, DW);
        float dh = fminf(d[3] * 0.2f, DW);
        float pcx = dx * w + cx, pcy = dy * h + cy;
        float pw = expf(dw) * w, ph = expf(dh) * h;
        float x1 = pcx - 0.5f * pw, y1 = pcy - 0.5f * ph;
        float x2 = pcx + 0.5f * pw, y2 = pcy + 0.5f * ph;
        x1 = fminf(fmaxf(x1, 0.f), 800.f); y1 = fminf(fmaxf(y1, 0.f), 800.f);
        x2 = fminf(fmaxf(x2, 0.f), 800.f); y2 = fminf(fmaxf(y2, 0.f), 800.f);
        float wv = x2 - x1, hv = y2 - y1;
        long oi = obase + t;
        Boxes[oi * 4 + 0] = x1; Boxes[oi * 4 + 1] = y1;
        Boxes[oi * 4 + 2] = x2; Boxes[oi * 4 + 3] = y2;
        Scores[oi] = score;
        Valid[oi] = (score >= 0.05f && wv >= 1.0f && hv >= 1.0f) ? 1 : 0;
    }
}

// ---------------- fused compaction + greedy NMS (one block per image) ----------------
__global__ void nms_fused(const float* __restrict__ Boxes, const float* __restrict__ Scores,
                          const unsigned char* __restrict__ Valid,
                          float* __restrict__ CB, int* __restrict__ CL,
                          float* __restrict__ CSw, float* __restrict__ out) {
    int img = blockIdx.x;
    int tid = threadIdx.x;  // 256
    const int SEG = 160;
    const unsigned char* V = Valid + (long)img * 40960;
    int j0 = tid * SEG;
    const unsigned int* V4 = (const unsigned int*)(V + j0);
    int c = 0;
    #pragma unroll
    for (int k = 0; k < 40; ++k) {
        unsigned int u = V4[k];
        c += (int)((u * 0x01010101u) >> 24);
    }
    __shared__ int cnt[256];
    cnt[tid] = c;
    __syncthreads();
    for (int d = 1; d < 256; d <<= 1) {
        int v = (tid >= d) ? cnt[tid - d] : 0;
        __syncthreads();
        cnt[tid] += v;
        __syncthreads();
    }
    int pos = cnt[tid] - c;
    const float* B = Boxes + (long)img * 40960 * 4;
    const float* S = Scores + (long)img * 40960;
    float* cb = CB + (long)img * 40960 * 4;
    float* sc = CSw + (long)img * 40960;
    int* cl = CL + (long)img * 40960;
    if (c > 0) {
        for (int k = 0; k < SEG; ++k) {
            int j = j0 + k;
            if (V[j]) {
                sc[pos] = S[j];
                cb[pos * 4 + 0] = B[j * 4 + 0]; cb[pos * 4 + 1] = B[j * 4 + 1];
                cb[pos * 4 + 2] = B[j * 4 + 2]; cb[pos * 4 + 3] = B[j * 4 + 3];
                cl[pos] = (j % 80) + 1;
                ++pos;
            }
        }
    }
    int Vn = cnt[255];
    for (int i = tid; i < 400; i += 256) out[img * 400 + i] = 0.f;
    if (tid < 100) {
        out[800 + img * 100 + tid] = 0.f;
        out[1000 + img * 100 + tid] = 0.f;
        out[1200 + img * 100 + tid] = 0.f;
    }
    __syncthreads();
    __shared__ float rv[256];
    __shared__ int ri[256];
    __shared__ float selbox[4];
    const float NEG = -__builtin_inff();
    for (int det = 0; det < 100; ++det) {
        float bv = NEG; int bi = -1;
        for (int j = tid; j < Vn; j += 256) {
            float s = sc[j];
            if (s > bv) { bv = s; bi = j; }
        }
        rv[tid] = bv; ri[tid] = bi;
        __syncthreads();
        for (int off = 128; off > 0; off >>= 1) {
            if (tid < off) {
                float ov = rv[tid + off]; int oi = ri[tid + off];
                if (ov > rv[tid] ||
                    (ov == rv[tid] && oi != -1 && (ri[tid] == -1 || oi < ri[tid]))) {
                    rv[tid] = ov; ri[tid] = oi;
                }
            }
            __syncthreads();
        }
        float mval = rv[0]; int mi = ri[0];
        if (!(mval > NEG) || mi < 0) break;
        if (tid == 0) {
            out[img * 400 + det * 4 + 0] = cb[mi * 4 + 0];
            out[img * 400 + det * 4 + 1] = cb[mi * 4 + 1];
            out[img * 400 + det * 4 + 2] = cb[mi * 4 + 2];
            out[img * 400 + det * 4 + 3] = cb[mi * 4 + 3];
            out[800 + img * 100 + det] = mval;
            out[1000 + img * 100 + det] = (float)cl[mi];
            out[1200 + img * 100 + det] = 1.0f;
            selbox[0] = cb[mi * 4 + 0]; selbox[1] = cb[mi * 4 + 1];
            selbox[2] = cb[mi * 4 + 2]; selbox[3] = cb[mi * 4 + 3];
            sc[mi] = NEG;
        }
        __syncthreads();
        float bx1 = selbox[0], by1 = selbox[1], bx2 = selbox[2], by2 = selbox[3];
        float a1 = (bx2 - bx1) * (by2 - by1);
        for (int j = tid; j < Vn; j += 256) {
            float s = sc[j];
            if (s == NEG) continue;
            float x1 = fmaxf(bx1, cb[j * 4 + 0]), y1 = fmaxf(by1, cb[j * 4 + 1]);
            float x2 = fminf(bx2, cb[j * 4 + 2]), y2 = fminf(by2, cb[j * 4 + 3]);
            float iw = fmaxf(x2 - x1, 0.f), ih = fmaxf(y2 - y1, 0.f);
            float inter = iw * ih;
            float a2 = (cb[j * 4 + 2] - cb[j * 4 + 0]) * (cb[j * 4 + 3] - cb[j * 4 + 1]);
            float iou = inter / (a1 + a2 - inter + 1e-9f);
            if (iou > 0.5f) sc[j] = NEG;
        }
        __syncthreads();
    }
}

extern "C" void kernel_launch(void* const* d_in, const int* in_sizes, int n_in,
                              void* d_out, int out_size, void* d_ws, size_t ws_size,
                              hipStream_t stream) {
    const float* features  = (const float*)d_in[0];
    const float* proposals = (const float*)d_in[1];
    const float* W1 = (const float*)d_in[2];
    const float* b1 = (const float*)d_in[3];
    const float* W2 = (const float*)d_in[4];
    const float* b2 = (const float*)d_in[5];
    const float* Wc = (const float*)d_in[6];
    const float* bc = (const float*)d_in[7];
    const float* Wb = (const float*)d_in[8];
    const float* bb = (const float*)d_in[9];

    // FC1 split-K tier by workspace (ws observed ~256MB)
    int zf1, kb1, kr1;
    if (ws_size >= 51380224UL + 16UL * 2097152UL + 3145728UL) { zf1 = 16; kb1 = 12; kr1 = 4; }
    else if (ws_size >= 51380224UL + 8UL * 2097152UL + 3145728UL) { zf1 = 8; kb1 = 24; kr1 = 4; }
    else { zf1 = 4; kb1 = 49; kr1 = 0; }

    char* ws = (char*)d_ws;
    // phase A
    short* Xb    = (short*)(ws);                      // 25,690,112 B
    short* W1t   = (short*)(ws + 25690112);           // 25,690,112 B
    short* featT = (short*)(ws + 51380224);           // 2,560,000 B (dead before P written)
    short* P     = (short*)(ws + 51380224);           // [zf1][1024][1024] bf16
    short* W2t_e = (short*)(ws + 51380224 + (size_t)zf1 * 2097152);  // 2MB
    short* Wht_e = (short*)((char*)W2t_e + 2097152);                 // 1MB ([512][1024], rows 405+ unused)
    // phase B (reuses ex-Xb region after FC1)
    short* H1b   = (short*)(ws);                      // 2 MB
    short* H2b   = (short*)(ws + 5242880);            // 2 MB
    float* Obuf  = (float*)(ws + 7340032);            // [1024][448] f32
    float* Boxes = (float*)(ws + 9175040);
    float* Scores= (float*)(ws + 10485760);
    unsigned char* Valid = (unsigned char*)(ws + 10813440);
    float* CB    = (float*)(ws + 10895360);
    int*   CL    = (int*)(ws + 12206080);
    float* CSw   = (float*)(ws + 12533760);

    // 1) features -> channel-last (small, must precede roi)
    featT_cvt<<<dim3(8, 79, 2), 256, 0, stream>>>(features, featT);
    // 2) roi-align || all weight transposes (independent; pipes overlap)
    prep_roi<<<15040, 256, 0, stream>>>(W1, W2, Wc, Wb, featT, proposals,
                                        W1t, W2t_e, Wht_e, Xb);

    // 3) FC1: dbuf 2-phase BK=64, z=16 split-K (r8 winner)
    gemm128<0><<<dim3(8, 8, zf1), 256, 0, stream>>>(Xb, W1t, nullptr, nullptr, (void*)P,
                                                    1024, 1024, 12544, kb1, kr1, 1024);
    reduceN_relu<<<512, 256, 0, stream>>>(P, b1, H1b, zf1);

    // 4) FC2 + head: direct dbuf BK=64 (r7 winner)
    gemm128<1><<<dim3(8, 8, 1), 256, 0, stream>>>(H1b, W2t_e, b2, nullptr, (void*)H2b,
                                                  1024, 1024, 1024, 16, 0, 1024);
    gemm128<2><<<dim3(4, 8, 1), 256, 0, stream>>>(H2b, Wht_e, bc, bb, (void*)Obuf,
                                                  1024, 448, 1024, 16, 0, 448);

    head_epilogue<<<1024, 64, 0, stream>>>(Obuf, proposals, Boxes, Scores, Valid);
    nms_fused<<<2, 256, 0, stream>>>(Boxes, Scores, Valid, CB, CL, CSw, (float*)d_out);
}

// Round 12
// 121.588 us; speedup vs baseline: 1.1416x; 1.0889x over previous
//
#include <hip/hip_runtime.h>
#include <hip/hip_bf16.h>

typedef __attribute__((ext_vector_type(8))) short short8;
typedef __attribute__((ext_vector_type(4))) float f32x4;

__device__ inline short f2bf(float x) {
    union { __hip_bfloat16 b; short s; } u;
    u.b = __float2bfloat16(x);
    return u.s;
}
__device__ inline float bf2f(short s) {
    union { __hip_bfloat16 b; short s; } u;
    u.s = s;
    return __bfloat162float(u.b);
}

#define GLDS16(g, l) __builtin_amdgcn_global_load_lds( \
    (const __attribute__((address_space(1))) void*)(g), \
    (__attribute__((address_space(3))) void*)(l), 16, 0, 0)

// ------- transpose v2: 64x64 tiles, float4 loads, short8 writes (128B segments) -------
// jobs: [0,3136) W1 | [3136,3456) features x2 | [3456,3712) W2 | [3712,3744) Wc
//       | [3744,3840) Wb.   in [R][C] f32 -> out [C][R] bf16.
__global__ __launch_bounds__(256) void transpose_v2(const float* __restrict__ W1,
                                                    const float* __restrict__ features,
                                                    const float* __restrict__ W2,
                                                    const float* __restrict__ Wc,
                                                    const float* __restrict__ Wb,
                                                    short* __restrict__ W1t,
                                                    short* __restrict__ featT,
                                                    short* __restrict__ W2t,
                                                    short* __restrict__ Wht) {
    __shared__ float tile[64][65];   // stride 65: all phases 2-way (free) bank aliasing
    int id = blockIdx.x;
    const float* in;
    short* out;
    int R, C, r0, c0;
    if (id < 3136) {
        in = W1; out = W1t; R = 12544; C = 1024;
        r0 = (id % 196) * 64; c0 = (id / 196) * 64;
    } else if (id < 3456) {
        int f = id - 3136;
        int img = f / 160, g = f % 160;
        in = features + (long)img * 640000;
        out = featT + (long)img * 640000;
        R = 256; C = 2500;
        r0 = (g % 4) * 64; c0 = (g / 4) * 64;
    } else if (id < 3712) {
        int g = id - 3456;
        in = W2; out = W2t; R = 1024; C = 1024;
        r0 = (g % 16) * 64; c0 = (g / 16) * 64;
    } else if (id < 3744) {
        int g = id - 3712;
        in = Wc; out = Wht; R = 1024; C = 81;
        r0 = (g % 16) * 64; c0 = (g / 16) * 64;
    } else {
        int g = id - 3744;
        in = Wb; out = Wht + 81 * 1024; R = 1024; C = 324;
        r0 = (g % 16) * 64; c0 = (g / 16) * 64;
    }
    int tid = threadIdx.x;
    int tr = tid >> 4, tc = tid & 15;
    if (c0 + 64 <= C) {
        #pragma unroll
        for (int i = 0; i < 4; ++i) {
            int r = r0 + tr + i * 16;
            float4 v = *(const float4*)(in + (long)r * C + c0 + tc * 4);
            tile[tr + i * 16][tc * 4 + 0] = v.x;
            tile[tr + i * 16][tc * 4 + 1] = v.y;
            tile[tr + i * 16][tc * 4 + 2] = v.z;
            tile[tr + i * 16][tc * 4 + 3] = v.w;
        }
    } else {
        #pragma unroll
        for (int i = 0; i < 4; ++i) {
            int r = r0 + tr + i * 16;
            #pragma unroll
            for (int e = 0; e < 4; ++e) {
                int c = c0 + tc * 4 + e;
                tile[tr + i * 16][tc * 4 + e] = (c < C) ? in[(long)r * C + c] : 0.f;
            }
        }
    }
    __syncthreads();
    #pragma unroll
    for (int p = 0; p < 2; ++p) {
        int n = (tid >> 3) + p * 32;       // output row (former col)
        int k0 = (tid & 7) * 8;            // 8 lanes x 16B = 128B contiguous per row
        if (c0 + n < C) {
            short8 o;
            #pragma unroll
            for (int j = 0; j < 8; ++j) o[j] = f2bf(tile[k0 + j][n]);
            *(short8*)(out + (long)(c0 + n) * R + r0 + k0) = o;
        }
    }
}

// ---------------- ROI-align v3: 16B vector loads, wave-half corner split ----------
__global__ __launch_bounds__(256) void roi_align_v3(const short* __restrict__ featT,
                                                    const float* __restrict__ props,
                                                    short* __restrict__ Xb) {
    int roi = blockIdx.x;
    int img = roi >> 9;
    __shared__ unsigned int soffB[784];
    __shared__ float swB[784];
    __shared__ float pbox[4];
    __shared__ short outb[49 * 264];
    int tid = threadIdx.x;
    if (tid < 4) pbox[tid] = props[roi * 4 + tid];
    __syncthreads();
    if (tid < 196) {
        float x1 = pbox[0] * 0.0625f, y1 = pbox[1] * 0.0625f;
        float x2 = pbox[2] * 0.0625f, y2 = pbox[3] * 0.0625f;
        float rw = fmaxf(x2 - x1, 1.0f), rh = fmaxf(y2 - y1, 1.0f);
        int p = tid >> 2, q = tid & 3;
        int py = p / 7, px = p % 7;
        int sy = q >> 1, sx = q & 1;
        int gy = py * 2 + sy, gx = px * 2 + sx;
        float gyv = ((float)gy + 0.5f) * 0.5f;
        float gxv = ((float)gx + 0.5f) * 0.5f;
        float ys = y1 + gyv * (rh * (1.0f / 7.0f));
        float xs = x1 + gxv * (rw * (1.0f / 7.0f));
        ys = fminf(fmaxf(ys, 0.0f), 49.0f);
        xs = fminf(fmaxf(xs, 0.0f), 49.0f);
        float y0f = floorf(ys), x0f = floorf(xs);
        int y0 = (int)y0f, x0 = (int)x0f;
        int y1i = min(y0 + 1, 49), x1i = min(x0 + 1, 49);
        float ly = ys - y0f, lx = xs - x0f;
        float hy = 1.f - ly, hx = 1.f - lx;
        int b00 = (y0 * 50 + x0) << 9;
        int ddx = (x1i - x0) << 9;
        int ddy = (y1i - y0) * 25600;
        int t4 = tid << 2;
        soffB[t4 + 0] = b00;             swB[t4 + 0] = hy * hx * 0.25f;
        soffB[t4 + 1] = b00 + ddx;       swB[t4 + 1] = hy * lx * 0.25f;
        soffB[t4 + 2] = b00 + ddy;       swB[t4 + 2] = ly * hx * 0.25f;
        soffB[t4 + 3] = b00 + ddy + ddx; swB[t4 + 3] = ly * lx * 0.25f;
    }
    __syncthreads();
    int w = tid >> 6, l = tid & 63;
    int half = l >> 5, ch16 = l & 31;
    const char* fbase = (const char*)featT + (long)img * 1280000 + (ch16 << 4);
    for (int p = w; p < 49; p += 4) {
        float acc[8] = {};
        #pragma unroll
        for (int ld = 0; ld < 8; ++ld) {
            int idx = (p << 4) + (ld << 1) + half;
            unsigned int off = soffB[idx];
            float wgt = swB[idx];
            short8 v = *(const short8*)(fbase + off);
            union { short8 s; unsigned int u[4]; } uv;
            uv.s = v;
            #pragma unroll
            for (int k2 = 0; k2 < 4; ++k2) {
                unsigned int u = uv.u[k2];
                float flo = __uint_as_float(u << 16);
                float fhi = __uint_as_float(u & 0xffff0000u);
                acc[k2 * 2]     += wgt * flo;
                acc[k2 * 2 + 1] += wgt * fhi;
            }
        }
        short8 o;
        #pragma unroll
        for (int j = 0; j < 8; ++j) {
            float t = acc[j] + __shfl_xor(acc[j], 32);
            o[j] = f2bf(t);
        }
        if (half == 0) *(short8*)&outb[p * 264 + (ch16 << 3)] = o;
    }
    __syncthreads();
    int c = tid / 49, r = tid % 49;
    short* xrow = Xb + (long)roi * 12544;
    #pragma unroll 1
    for (int i = 0; i < 49; ++i) {
        xrow[tid + i * 256] = outb[r * 264 + c];
        c += 5; r += 11;
        if (r >= 49) { r -= 49; c += 1; }
    }
}

// ---------------- 128x128 MFMA GEMM, glds + XOR swizzle + dbuf 2-phase ----------------
// MODE 0: partial -> bf16 at Cout + z*M*N; MODE 1: bias+relu -> bf16; MODE 2: bias -> f32
template <int MODE>
__global__ __launch_bounds__(256) void gemm128(const short* __restrict__ A,
                                               const short* __restrict__ Bt,
                                               const float* __restrict__ bias,
                                               const float* __restrict__ bias2,
                                               void* __restrict__ Cout,
                                               int M, int N, int K, int kbase, int krem,
                                               int Ncap) {
    __shared__ short As[2][128 * 64];
    __shared__ short Bs[2][128 * 64];
    int gx = gridDim.x, gy = gridDim.y;
    int nwg = gx * gy * gridDim.z;
    int orig = blockIdx.x + gx * (blockIdx.y + gy * blockIdx.z);
    int wg = orig;
    if ((nwg & 7) == 0 && nwg >= 64) {
        int q = nwg >> 3;
        wg = (orig & 7) * q + (orig >> 3);
    }
    int bx_ = wg % gx;
    int tmp = wg / gx;
    int by_ = tmp % gy;
    int bz_ = tmp / gy;
    int ksteps = kbase + (bz_ < krem ? 1 : 0);
    long kbeg = ((long)bz_ * kbase + (bz_ < krem ? bz_ : krem)) * 64;
    int m0 = by_ * 128, n0 = bx_ * 128;
    int tid = threadIdx.x;
    int w = tid >> 6, lane = tid & 63;
    int wr = w >> 1, wc = w & 1;
    int lr = lane & 15, lk = lane >> 4;
    int srow = tid >> 3;
    int sbx = ((tid & 7) ^ (srow & 7)) << 4;
    const char* Ag = (const char*)A + ((long)(m0 + srow) * K + kbeg) * 2 + sbx;
    const char* Bg = (const char*)Bt + ((long)(n0 + srow) * K + kbeg) * 2 + sbx;
    const long rstep = (long)K * 64;
    char* As0 = (char*)&As[0][0];
    char* Bs0 = (char*)&Bs[0][0];
    int wofs = w << 10;
    int sw = (lr & 7) << 4;
    f32x4 acc[4][4] = {};

    #pragma unroll
    for (int i = 0; i < 4; ++i) {
        GLDS16(Ag + i * rstep, As0 + wofs + i * 4096);
        GLDS16(Bg + i * rstep, Bs0 + wofs + i * 4096);
    }
    __syncthreads();
    int cur = 0;
    for (int t = 0; t < ksteps; ++t) {
        if (t + 1 < ksteps) {
            const char* a = Ag + (long)(t + 1) * 128;
            const char* b = Bg + (long)(t + 1) * 128;
            char* ad = As0 + ((cur ^ 1) << 14) + wofs;
            char* bd = Bs0 + ((cur ^ 1) << 14) + wofs;
            #pragma unroll
            for (int i = 0; i < 4; ++i) {
                GLDS16(a + i * rstep, ad + i * 4096);
                GLDS16(b + i * rstep, bd + i * 4096);
            }
        }
        const char* as = As0 + (cur << 14);
        const char* bs = Bs0 + (cur << 14);
        #pragma unroll
        for (int kk = 0; kk < 2; ++kk) {
            short8 av[4], bv[4];
            #pragma unroll
            for (int f = 0; f < 4; ++f) {
                av[f] = *(const short8*)(as + (wr * 64 + f * 16 + lr) * 128 + ((kk * 64 + lk * 16) ^ sw));
                bv[f] = *(const short8*)(bs + (wc * 64 + f * 16 + lr) * 128 + ((kk * 64 + lk * 16) ^ sw));
            }
            #pragma unroll
            for (int fm = 0; fm < 4; ++fm)
                #pragma unroll
                for (int fn = 0; fn < 4; ++fn)
                    acc[fm][fn] = __builtin_amdgcn_mfma_f32_16x16x32_bf16(av[fm], bv[fn], acc[fm][fn], 0, 0, 0);
        }
        __syncthreads();
        cur ^= 1;
    }
    #pragma unroll
    for (int fm = 0; fm < 4; ++fm) {
        #pragma unroll
        for (int fn = 0; fn < 4; ++fn) {
            int col = n0 + wc * 64 + fn * 16 + lr;
            float bv = 0.f;
            if (MODE == 1) bv = bias[col];
            if (MODE == 2) bv = (col < 81) ? bias[col] : (col < 405 ? bias2[col - 81] : 0.f);
            #pragma unroll
            for (int j = 0; j < 4; ++j) {
                int row = m0 + wr * 64 + fm * 16 + lk * 4 + j;
                float v = acc[fm][fn][j];
                if (MODE == 0) {
                    ((short*)Cout)[(long)bz_ * M * N + (long)row * N + col] = f2bf(v);
                } else if (MODE == 1) {
                    ((short*)Cout)[(long)row * N + col] = f2bf(fmaxf(v + bv, 0.f));
                } else {
                    if (col < Ncap) ((float*)Cout)[(long)row * N + col] = v + bv;
                }
            }
        }
    }
}

// ---------------- split-K reduce: H1 = relu(sum_s P[s] + b1) -> bf16 ----------------
__global__ void reduceN_relu(const short* __restrict__ P, const float* __restrict__ bias,
                             short* __restrict__ Hout, int nsl) {
    long i0 = ((long)blockIdx.x * 256 + threadIdx.x) * 8;
    int col = (int)(i0 & 1023);
    float v[8];
    #pragma unroll
    for (int j = 0; j < 8; ++j) v[j] = bias[col + j];
    for (int s = 0; s < nsl; ++s) {
        short8 p = *(const short8*)(P + (long)s * 1048576 + i0);
        #pragma unroll
        for (int j = 0; j < 8; ++j) v[j] += bf2f(p[j]);
    }
    short8 o;
    #pragma unroll
    for (int j = 0; j < 8; ++j) o[j] = f2bf(fmaxf(v[j], 0.f));
    *(short8*)(Hout + i0) = o;
}

// ---------------- softmax + decode + valid ----------------
__global__ void head_epilogue(const float* __restrict__ O,      // [1024][448]
                              const float* __restrict__ props,
                              float* __restrict__ Boxes,
                              float* __restrict__ Scores,
                              unsigned char* __restrict__ Valid) {
    int roi = blockIdx.x;
    int lane = threadIdx.x;  // 64
    const float* o = O + (long)roi * 448;
    float m = -1e30f;
    for (int i = lane; i < 81; i += 64) m = fmaxf(m, o[i]);
    for (int off = 32; off > 0; off >>= 1) m = fmaxf(m, __shfl_xor(m, off));
    float ssum = 0.f;
    for (int i = lane; i < 81; i += 64) ssum += expf(o[i] - m);
    for (int off = 32; off > 0; off >>= 1) ssum += __shfl_xor(ssum, off);
    float inv = 1.0f / ssum;
    int img = roi >> 9, rb = roi & 511;
    float px1 = props[roi * 4 + 0], py1 = props[roi * 4 + 1];
    float px2 = props[roi * 4 + 2], py2 = props[roi * 4 + 3];
    float w = px2 - px1, h = py2 - py1;
    float cx = px1 + 0.5f * w, cy = py1 + 0.5f * h;
    long obase = (long)img * 40960 + (long)rb * 80;
    const float DW = 4.135166556742356f;
    for (int t = lane; t < 80; t += 64) {
        int cls = t + 1;
        float score = expf(o[cls] - m) * inv;
        const float* d = o + 81 + cls * 4;
        float dx = d[0] * 0.1f, dy = d[1] * 0.1f;
        float dw = fminf(d[2] * 0.2f, DW);
        float dh = fminf(d[3] * 0.2f, DW);
        float pcx = dx * w + cx, pcy = dy * h + cy;
        float pw = expf(dw) * w, ph = expf(dh) * h;
        float x1 = pcx - 0.5f * pw, y1 = pcy - 0.5f * ph;
        float x2 = pcx + 0.5f * pw, y2 = pcy + 0.5f * ph;
        x1 = fminf(fmaxf(x1, 0.f), 800.f); y1 = fminf(fmaxf(y1, 0.f), 800.f);
        x2 = fminf(fmaxf(x2, 0.f), 800.f); y2 = fminf(fmaxf(y2, 0.f), 800.f);
        float wv = x2 - x1, hv = y2 - y1;
        long oi = obase + t;
        Boxes[oi * 4 + 0] = x1; Boxes[oi * 4 + 1] = y1;
        Boxes[oi * 4 + 2] = x2; Boxes[oi * 4 + 3] = y2;
        Scores[oi] = score;
        Valid[oi] = (score >= 0.05f && wv >= 1.0f && hv >= 1.0f) ? 1 : 0;
    }
}

// ---------------- fused compaction + greedy NMS (one block per image) ----------------
__global__ void nms_fused(const float* __restrict__ Boxes, const float* __restrict__ Scores,
                          const unsigned char* __restrict__ Valid,
                          float* __restrict__ CB, int* __restrict__ CL,
                          float* __restrict__ CSw, float* __restrict__ out) {
    int img = blockIdx.x;
    int tid = threadIdx.x;  // 256
    const int SEG = 160;
    const unsigned char* V = Valid + (long)img * 40960;
    int j0 = tid * SEG;
    const unsigned int* V4 = (const unsigned int*)(V + j0);
    int c = 0;
    #pragma unroll
    for (int k = 0; k < 40; ++k) {
        unsigned int u = V4[k];
        c += (int)((u * 0x01010101u) >> 24);
    }
    __shared__ int cnt[256];
    cnt[tid] = c;
    __syncthreads();
    for (int d = 1; d < 256; d <<= 1) {
        int v = (tid >= d) ? cnt[tid - d] : 0;
        __syncthreads();
        cnt[tid] += v;
        __syncthreads();
    }
    int pos = cnt[tid] - c;
    const float* B = Boxes + (long)img * 40960 * 4;
    const float* S = Scores + (long)img * 40960;
    float* cb = CB + (long)img * 40960 * 4;
    float* sc = CSw + (long)img * 40960;
    int* cl = CL + (long)img * 40960;
    if (c > 0) {
        for (int k = 0; k < SEG; ++k) {
            int j = j0 + k;
            if (V[j]) {
                sc[pos] = S[j];
                cb[pos * 4 + 0] = B[j * 4 + 0]; cb[pos * 4 + 1] = B[j * 4 + 1];
                cb[pos * 4 + 2] = B[j * 4 + 2]; cb[pos * 4 + 3] = B[j * 4 + 3];
                cl[pos] = (j % 80) + 1;
                ++pos;
            }
        }
    }
    int Vn = cnt[255];
    for (int i = tid; i < 400; i += 256) out[img * 400 + i] = 0.f;
    if (tid < 100) {
        out[800 + img * 100 + tid] = 0.f;
        out[1000 + img * 100 + tid] = 0.f;
        out[1200 + img * 100 + tid] = 0.f;
    }
    __syncthreads();
    __shared__ float rv[256];
    __shared__ int ri[256];
    __shared__ float selbox[4];
    const float NEG = -__builtin_inff();
    for (int det = 0; det < 100; ++det) {
        float bv = NEG; int bi = -1;
        for (int j = tid; j < Vn; j += 256) {
            float s = sc[j];
            if (s > bv) { bv = s; bi = j; }
        }
        rv[tid] = bv; ri[tid] = bi;
        __syncthreads();
        for (int off = 128; off > 0; off >>= 1) {
            if (tid < off) {
                float ov = rv[tid + off]; int oi = ri[tid + off];
                if (ov > rv[tid] ||
                    (ov == rv[tid] && oi != -1 && (ri[tid] == -1 || oi < ri[tid]))) {
                    rv[tid] = ov; ri[tid] = oi;
                }
            }
            __syncthreads();
        }
        float mval = rv[0]; int mi = ri[0];
        if (!(mval > NEG) || mi < 0) break;
        if (tid == 0) {
            out[img * 400 + det * 4 + 0] = cb[mi * 4 + 0];
            out[img * 400 + det * 4 + 1] = cb[mi * 4 + 1];
            out[img * 400 + det * 4 + 2] = cb[mi * 4 + 2];
            out[img * 400 + det * 4 + 3] = cb[mi * 4 + 3];
            out[800 + img * 100 + det] = mval;
            out[1000 + img * 100 + det] = (float)cl[mi];
            out[1200 + img * 100 + det] = 1.0f;
            selbox[0] = cb[mi * 4 + 0]; selbox[1] = cb[mi * 4 + 1];
            selbox[2] = cb[mi * 4 + 2]; selbox[3] = cb[mi * 4 + 3];
            sc[mi] = NEG;
        }
        __syncthreads();
        float bx1 = selbox[0], by1 = selbox[1], bx2 = selbox[2], by2 = selbox[3];
        float a1 = (bx2 - bx1) * (by2 - by1);
        for (int j = tid; j < Vn; j += 256) {
            float s = sc[j];
            if (s == NEG) continue;
            float x1 = fmaxf(bx1, cb[j * 4 + 0]), y1 = fmaxf(by1, cb[j * 4 + 1]);
            float x2 = fminf(bx2, cb[j * 4 + 2]), y2 = fminf(by2, cb[j * 4 + 3]);
            float iw = fmaxf(x2 - x1, 0.f), ih = fmaxf(y2 - y1, 0.f);
            float inter = iw * ih;
            float a2 = (cb[j * 4 + 2] - cb[j * 4 + 0]) * (cb[j * 4 + 3] - cb[j * 4 + 1]);
            float iou = inter / (a1 + a2 - inter + 1e-9f);
            if (iou > 0.5f) sc[j] = NEG;
        }
        __syncthreads();
    }
}

extern "C" void kernel_launch(void* const* d_in, const int* in_sizes, int n_in,
                              void* d_out, int out_size, void* d_ws, size_t ws_size,
                              hipStream_t stream) {
    const float* features  = (const float*)d_in[0];
    const float* proposals = (const float*)d_in[1];
    const float* W1 = (const float*)d_in[2];
    const float* b1 = (const float*)d_in[3];
    const float* W2 = (const float*)d_in[4];
    const float* b2 = (const float*)d_in[5];
    const float* Wc = (const float*)d_in[6];
    const float* bc = (const float*)d_in[7];
    const float* Wb = (const float*)d_in[8];
    const float* bb = (const float*)d_in[9];

    // FC1 split-K tier by workspace (z=8 is the r7 winner)
    int zf1, kb1, kr1;
    if (ws_size >= 51380224UL + 8UL * 2097152UL + 3145728UL) { zf1 = 8; kb1 = 24; kr1 = 4; }
    else { zf1 = 4; kb1 = 49; kr1 = 0; }

    char* ws = (char*)d_ws;
    // phase A
    short* Xb    = (short*)(ws);                      // 25,690,112 B
    short* W1t   = (short*)(ws + 25690112);           // 25,690,112 B
    short* featT = (short*)(ws + 51380224);           // 2,560,000 B (dead before P written)
    short* P     = (short*)(ws + 51380224);           // [zf1][1024][1024] bf16
    short* W2t_e = (short*)(ws + 51380224 + (size_t)zf1 * 2097152);  // 2MB
    short* Wht_e = (short*)((char*)W2t_e + 2097152);                 // 1MB ([512][1024], rows 405+ unused)
    // phase B (reuses ex-Xb region after FC1)
    short* H1b   = (short*)(ws);                      // 2 MB
    short* H2b   = (short*)(ws + 5242880);            // 2 MB
    float* Obuf  = (float*)(ws + 7340032);            // [1024][448] f32
    float* Boxes = (float*)(ws + 9175040);
    float* Scores= (float*)(ws + 10485760);
    unsigned char* Valid = (unsigned char*)(ws + 10813440);
    float* CB    = (float*)(ws + 10895360);
    int*   CL    = (int*)(ws + 12206080);
    float* CSw   = (float*)(ws + 12533760);

    // 1) all transposes (weights + features), vectorized 64x64 tiles
    transpose_v2<<<3840, 256, 0, stream>>>(W1, features, W2, Wc, Wb,
                                           W1t, featT, W2t_e, Wht_e);
    // 2) roi-align
    roi_align_v3<<<1024, 256, 0, stream>>>(featT, proposals, Xb);

    // 3) FC1: dbuf 2-phase BK=64, z=8 split-K (r7 winner)
    gemm128<0><<<dim3(8, 8, zf1), 256, 0, stream>>>(Xb, W1t, nullptr, nullptr, (void*)P,
                                                    1024, 1024, 12544, kb1, kr1, 1024);
    reduceN_relu<<<512, 256, 0, stream>>>(P, b1, H1b, zf1);

    // 4) FC2 + head: direct dbuf BK=64 (r7 winner)
    gemm128<1><<<dim3(8, 8, 1), 256, 0, stream>>>(H1b, W2t_e, b2, nullptr, (void*)H2b,
                                                  1024, 1024, 1024, 16, 0, 1024);
    gemm128<2><<<dim3(4, 8, 1), 256, 0, stream>>>(H2b, Wht_e, bc, bb, (void*)Obuf,
                                                  1024, 448, 1024, 16, 0, 448);

    head_epilogue<<<1024, 64, 0, stream>>>(Obuf, proposals, Boxes, Scores, Valid);
    nms_fused<<<2, 256, 0, stream>>>(Boxes, Scores, Valid, CB, CL, CSw, (float*)d_out);
}